// Round 1
// baseline (3522.178 us; speedup 1.0000x reference)
//
#include <hip/hip_runtime.h>
#include <math.h>

#define Bsz 8
#define Nsz 2048
#define Ksz 8
#define NSLOPE 0.2f
#define EPSV 1e-5f

// ------------------------------------------------------------------
// Tiled fp32 SGEMM: C[b] = A @ B[b], 64x64 tile, BK=16, 4x4/thread.
// ATRANS=0: A row-major (M x K), lda = K-stride.
// ATRANS=1: A stored (K x M) row-major (used for pair = prev^T @ prev).
// EPI=0: plain store. EPI=1: pair epilogue -((xx[m] - 2*acc) + xx[n]).
// ------------------------------------------------------------------
template <int ATRANS, int EPI>
__launch_bounds__(256) __global__
void sgemm_k(const float* __restrict__ A, long long sAb, int lda,
             const float* __restrict__ Bm, long long sBb, int ldb,
             float* __restrict__ C, long long sCb, int ldc,
             int M, int Kk, const float* __restrict__ xx)
{
    __shared__ float As[16][64];
    __shared__ float Bs[16][64];
    const int b = blockIdx.z;
    const float* Ab = A + (long long)b * sAb;
    const float* Bb = Bm + (long long)b * sBb;
    const int m0 = blockIdx.y * 64, n0 = blockIdx.x * 64;
    const int tid = threadIdx.x;
    const int am = tid >> 2, ak = (tid & 3) * 4;
    const int bk = tid >> 6, bn = tid & 63;
    const int tx = tid & 15, ty = tid >> 4;
    float acc[4][4] = {};
    for (int k0 = 0; k0 < Kk; k0 += 16) {
        if (ATRANS) {
#pragma unroll
            for (int i = 0; i < 4; i++) {
                int kk = bk + i * 4;
                int gk = k0 + kk;
                As[kk][bn] = (gk < Kk) ? Ab[(long long)gk * lda + (m0 + bn)] : 0.f;
            }
        } else {
#pragma unroll
            for (int i = 0; i < 4; i++) {
                int gk = k0 + ak + i;
                int gm = m0 + am;
                As[ak + i][am] = (gk < Kk && gm < M) ? Ab[(long long)gm * lda + gk] : 0.f;
            }
        }
#pragma unroll
        for (int i = 0; i < 4; i++) {
            int kk = bk + i * 4;
            int gk = k0 + kk;
            Bs[kk][bn] = (gk < Kk) ? Bb[(long long)gk * ldb + (n0 + bn)] : 0.f;
        }
        __syncthreads();
#pragma unroll
        for (int kk = 0; kk < 16; kk++) {
            float a[4], bb2[4];
#pragma unroll
            for (int i = 0; i < 4; i++) a[i] = As[kk][ty * 4 + i];
#pragma unroll
            for (int j = 0; j < 4; j++) bb2[j] = Bs[kk][tx * 4 + j];
#pragma unroll
            for (int i = 0; i < 4; i++)
#pragma unroll
                for (int j = 0; j < 4; j++)
                    acc[i][j] = fmaf(a[i], bb2[j], acc[i][j]);
        }
        __syncthreads();
    }
    float* Cb = C + (long long)b * sCb;
#pragma unroll
    for (int i = 0; i < 4; i++) {
        int gm = m0 + ty * 4 + i;
        if (gm >= M) continue;
#pragma unroll
        for (int j = 0; j < 4; j++) {
            int gn = n0 + tx * 4 + j;
            float v = acc[i][j];
            if (EPI == 1) v = -((xx[gm] - 2.f * v) + xx[gn]);
            Cb[(long long)gm * ldc + gn] = v;
        }
    }
}

// xt[b,c,n] = x[b,n,c]
__global__ void transpose_x_k(const float* __restrict__ x, float* __restrict__ xt)
{
    int t = blockIdx.x * 256 + threadIdx.x;
    if (t >= Bsz * Nsz) return;
    int n = t & (Nsz - 1), b = t >> 11;
#pragma unroll
    for (int c = 0; c < 3; c++)
        xt[((size_t)b * 3 + c) * Nsz + n] = x[((size_t)b * Nsz + n) * 3 + c];
}

// wc rows [0,O): W[:, :C];  rows [O,2O): W[:, C:] - W[:, :C]
__global__ void prep_w_k(const float* __restrict__ W, float* __restrict__ wc, int O, int C)
{
    int t = blockIdx.x * 256 + threadIdx.x;
    if (t >= O * C) return;
    int oo = t / C, c = t % C;
    float a = W[(size_t)oo * 2 * C + c];
    float b2 = W[(size_t)oo * 2 * C + C + c];
    wc[(size_t)oo * C + c] = a;
    wc[(size_t)(O + oo) * C + c] = b2 - a;
}

// xx[b,n] = sum_c prev[b,c,n]^2 ; prev has per-b stride 960*N (lives inside cat)
__global__ void compute_xx_k(const float* __restrict__ prev, float* __restrict__ xx, int C)
{
    int t = blockIdx.x * 256 + threadIdx.x;
    if (t >= Bsz * Nsz) return;
    int n = t & (Nsz - 1), b = t >> 11;
    const float* p = prev + (size_t)b * 960 * Nsz + n;
    float s = 0.f;
    for (int c = 0; c < C; c++) { float v = p[(size_t)c * Nsz]; s = fmaf(v, v, s); }
    xx[t] = s;
}

// top-8 indices per row of pair (one batch), JAX semantics: value desc, ties -> lower index.
__global__ void topk8_k(const float* __restrict__ pair, int* __restrict__ idxo)
{
    int lane = threadIdx.x & 63;
    int wv = threadIdx.x >> 6;
    int row = blockIdx.x * 4 + wv;
    const float* pr = pair + (size_t)row * Nsz;
    int chosen[8];
#pragma unroll
    for (int r = 0; r < 8; r++) {
        float bv = -INFINITY; int bi = 0x7fffffff;
        for (int m = lane; m < Nsz; m += 64) {
            bool skip = false;
#pragma unroll
            for (int q = 0; q < 8; q++)
                if (q < r && chosen[q] == m) skip = true;
            float v = pr[m];
            if (!skip && v > bv) { bv = v; bi = m; }
        }
#pragma unroll
        for (int off = 32; off; off >>= 1) {
            float ov = __shfl_xor(bv, off, 64);
            int oi = __shfl_xor(bi, off, 64);
            if (ov > bv || (ov == bv && oi < bi)) { bv = ov; bi = oi; }
        }
        chosen[r] = bi;
        if (lane == 0) idxo[row * 8 + r] = bi;
    }
}

// h[b,o,n,k] = P[b,o,idx[b,n,k]] + Q[b,o,n]; writes max_k h into cat; partial sums of h,h^2.
// block = (64,4); grid = (N/64, O/4, B). part layout: [o][b][blk]{s1,s2}
__global__ void gather_pool_k(const float* __restrict__ R, const int* __restrict__ idx,
                              float* __restrict__ cat, float* __restrict__ part,
                              int O, int catOff)
{
    int lane = threadIdx.x;
    int os = threadIdx.y;
    int n = blockIdx.x * 64 + lane;
    int o = blockIdx.y * 4 + os;
    int b = blockIdx.z;
    const float* P = R + ((size_t)b * 2 * O + o) * Nsz;
    const float* Q = P + (size_t)O * Nsz;
    const int* id = idx + ((size_t)b * Nsz + n) * 8;
    float q = Q[n];
    float hmax = -INFINITY, s1 = 0.f, s2 = 0.f;
#pragma unroll
    for (int k = 0; k < 8; k++) {
        float h = P[id[k]] + q;
        hmax = fmaxf(hmax, h);
        s1 += h;
        s2 += h * h;
    }
    cat[((size_t)b * 960 + catOff + o) * Nsz + n] = hmax;
#pragma unroll
    for (int off = 32; off; off >>= 1) { s1 += __shfl_xor(s1, off, 64); s2 += __shfl_xor(s2, off, 64); }
    if (lane == 0) {
        size_t pi = ((size_t)o * Bsz + b) * 32 + blockIdx.x;
        part[pi * 2] = s1;
        part[pi * 2 + 1] = s2;
    }
}

// reduce 256 partials per channel -> stats[2o]=sum, stats[2o+1]=sumsq (deterministic)
__global__ void stats_reduce_k(const float* __restrict__ part, float* __restrict__ stats)
{
    int o2 = blockIdx.x;
    int t = threadIdx.x;
    float s1 = part[((size_t)o2 * 256 + t) * 2];
    float s2 = part[((size_t)o2 * 256 + t) * 2 + 1];
#pragma unroll
    for (int off = 32; off; off >>= 1) { s1 += __shfl_xor(s1, off, 64); s2 += __shfl_xor(s2, off, 64); }
    __shared__ float sh[8];
    int w = t >> 6;
    if ((t & 63) == 0) { sh[w] = s1; sh[4 + w] = s2; }
    __syncthreads();
    if (t == 0) {
        stats[2 * o2] = sh[0] + sh[1] + sh[2] + sh[3];
        stats[2 * o2 + 1] = sh[4] + sh[5] + sh[6] + sh[7];
    }
}

// per-channel stats over (B,N) for fc tensors (B,O,N), deterministic
__global__ void fc_stats_k(const float* __restrict__ buf, float* __restrict__ stats, int O)
{
    int oo = blockIdx.x;
    int t = threadIdx.x;
    float s1 = 0.f, s2 = 0.f;
    for (int i = t; i < Bsz * Nsz; i += 256) {
        int b = i >> 11, n = i & (Nsz - 1);
        float v = buf[((size_t)b * O + oo) * Nsz + n];
        s1 += v; s2 += v * v;
    }
#pragma unroll
    for (int off = 32; off; off >>= 1) { s1 += __shfl_xor(s1, off, 64); s2 += __shfl_xor(s2, off, 64); }
    __shared__ float sh[8];
    int w = t >> 6;
    if ((t & 63) == 0) { sh[w] = s1; sh[4 + w] = s2; }
    __syncthreads();
    if (t == 0) {
        stats[2 * oo] = sh[0] + sh[1] + sh[2] + sh[3];
        stats[2 * oo + 1] = sh[4] + sh[5] + sh[6] + sh[7];
    }
}

// in-place lrelu((x - mean)/sqrt(var+eps)) over (B,O,N) slice of buf (channel offset off, total Ctot)
__global__ void bn_lrelu_k(float* __restrict__ buf, const float* __restrict__ stats,
                           int Ctot, int off, int O, float invCnt)
{
    size_t t = (size_t)blockIdx.x * 256 + threadIdx.x;
    size_t total = (size_t)Bsz * O * Nsz;
    if (t >= total) return;
    int n = (int)(t & (Nsz - 1));
    size_t t2 = t >> 11;
    int oo = (int)(t2 % O);
    int b = (int)(t2 / O);
    float mean = stats[2 * oo] * invCnt;
    float var = stats[2 * oo + 1] * invCnt - mean * mean;
    float* p = buf + ((size_t)b * Ctot + off + oo) * Nsz + n;
    float v = (*p - mean) / sqrtf(var + EPSV);
    *p = v >= 0.f ? v : NSLOPE * v;
}

// argmax_n(logits + gumbel(u)) per (b,o) row; write exact one-hot to out (70,B,N,1)
__global__ void gumbel_onehot_k(const float* __restrict__ logits, const float* __restrict__ u,
                                float* __restrict__ out)
{
    int lane = threadIdx.x & 63;
    int wv = threadIdx.x >> 6;
    int row = blockIdx.x * 4 + wv;      // row = b*70 + o
    int b = row / 70, oo = row % 70;
    const float* L = logits + (size_t)row * Nsz;
    const float* U = u + (size_t)row * Nsz;
    float bv = -INFINITY; int bi = 0x7fffffff;
    for (int n = lane; n < Nsz; n += 64) {
        float g = -logf(-logf(U[n]));
        float z = L[n] + g;
        if (z > bv) { bv = z; bi = n; }
    }
#pragma unroll
    for (int off = 32; off; off >>= 1) {
        float ov = __shfl_xor(bv, off, 64);
        int oi = __shfl_xor(bi, off, 64);
        if (ov > bv || (ov == bv && oi < bi)) { bv = ov; bi = oi; }
    }
    float* Or = out + ((size_t)oo * Bsz + b) * Nsz;
    for (int n = lane; n < Nsz; n += 64) Or[n] = (n == bi) ? 1.f : 0.f;
}

extern "C" void kernel_launch(void* const* d_in, const int* in_sizes, int n_in,
                              void* d_out, int out_size, void* d_ws, size_t ws_size,
                              hipStream_t stream)
{
    (void)in_sizes; (void)n_in; (void)out_size; (void)ws_size;
    const float* x   = (const float*)d_in[0];
    const int*   sn  = (const int*)d_in[1];
    const float* un  = (const float*)d_in[2];
    const float* W0  = (const float*)d_in[3];
    const float* W1  = (const float*)d_in[4];
    const float* W2  = (const float*)d_in[5];
    const float* W3  = (const float*)d_in[6];
    const float* W4  = (const float*)d_in[7];
    const float* Wm1 = (const float*)d_in[8];
    const float* Wm2 = (const float*)d_in[9];
    float* out = (float*)d_out;

    float* ws = (float*)d_ws;
    size_t o = 0;
    float* cat  = ws + o; o += (size_t)Bsz * 960 * Nsz;   // 62.9 MB: out0..out3 concat
    float* Rbuf = ws + o; o += (size_t)Bsz * 1024 * Nsz;  // 67 MB: P/Q stack; later feat
    float* pair = ws + o; o += (size_t)Nsz * Nsz;         // 16.8 MB per-batch pair; later logits
    float* xt   = ws + o; o += (size_t)Bsz * 3 * Nsz;
    float* xxb  = ws + o; o += (size_t)Bsz * Nsz;
    float* wcat = ws + o; o += (size_t)1024 * 256;
    float* part = ws + o; o += (size_t)1024 * 256 * 2;
    float* stats= ws + o; o += 2048;
    int* idxb   = (int*)(ws + o); o += (size_t)Bsz * Nsz * Ksz;
    float* feat   = Rbuf;  // alias: R dead after L4 gather
    float* hm     = cat;   // alias: cat dead after W4 gemm
    float* logits = pair;  // alias: pair dead after last knn

    transpose_x_k<<<(Bsz * Nsz + 255) / 256, 256, 0, stream>>>(x, xt);

    // ---- edge layer 1 (C=3, O=64, idx = start_neighs) ----
    prep_w_k<<<1, 256, 0, stream>>>(W0, wcat, 64, 3);
    sgemm_k<0, 0><<<dim3(32, 2, Bsz), 256, 0, stream>>>(wcat, 0, 3, xt, 3LL * Nsz, Nsz,
                                                        Rbuf, 2LL * 64 * Nsz, Nsz, 128, 3, nullptr);
    gather_pool_k<<<dim3(32, 16, Bsz), dim3(64, 4), 0, stream>>>(Rbuf, sn, cat, part, 64, 0);
    stats_reduce_k<<<64, 256, 0, stream>>>(part, stats);
    bn_lrelu_k<<<(int)(((size_t)Bsz * 64 * Nsz + 255) / 256), 256, 0, stream>>>(
        cat, stats, 960, 0, 64, 1.f / 131072.f);

    // ---- edge layers 2..4 with knn rebuild ----
    struct LayerDesc { const float* W; int C; int O; int prevOff; int catOff; };
    LayerDesc L[3] = {
        { W1, 64, 128, 0, 64 },
        { W2, 128, 256, 64, 192 },
        { W3, 256, 512, 192, 448 },
    };
    for (int li = 0; li < 3; li++) {
        int C = L[li].C, O = L[li].O;
        const float* prev = cat + (size_t)L[li].prevOff * Nsz;
        compute_xx_k<<<(Bsz * Nsz + 255) / 256, 256, 0, stream>>>(prev, xxb, C);
        for (int b = 0; b < Bsz; b++) {
            const float* pb = prev + (size_t)b * 960 * Nsz;
            sgemm_k<1, 1><<<dim3(32, 32, 1), 256, 0, stream>>>(pb, 0, Nsz, pb, 0, Nsz,
                pair, 0, Nsz, Nsz, C, xxb + (size_t)b * Nsz);
            topk8_k<<<Nsz / 4, 256, 0, stream>>>(pair, idxb + (size_t)b * Nsz * Ksz);
        }
        prep_w_k<<<(O * C + 255) / 256, 256, 0, stream>>>(L[li].W, wcat, O, C);
        sgemm_k<0, 0><<<dim3(32, 2 * O / 64, Bsz), 256, 0, stream>>>(wcat, 0, C, prev, 960LL * Nsz, Nsz,
            Rbuf, 2LL * O * Nsz, Nsz, 2 * O, C, nullptr);
        gather_pool_k<<<dim3(32, O / 4, Bsz), dim3(64, 4), 0, stream>>>(Rbuf, idxb, cat, part, O, L[li].catOff);
        stats_reduce_k<<<O, 256, 0, stream>>>(part, stats);
        bn_lrelu_k<<<(int)(((size_t)Bsz * O * Nsz + 255) / 256), 256, 0, stream>>>(
            cat, stats, 960, L[li].catOff, O, 1.f / 131072.f);
    }

    // ---- fc head ----
    sgemm_k<0, 0><<<dim3(32, 16, Bsz), 256, 0, stream>>>(W4, 0, 960, cat, 960LL * Nsz, Nsz,
        feat, 1024LL * Nsz, Nsz, 1024, 960, nullptr);
    fc_stats_k<<<1024, 256, 0, stream>>>(feat, stats, 1024);
    bn_lrelu_k<<<(int)(((size_t)Bsz * 1024 * Nsz + 255) / 256), 256, 0, stream>>>(
        feat, stats, 1024, 0, 1024, 1.f / 16384.f);

    sgemm_k<0, 0><<<dim3(32, 8, Bsz), 256, 0, stream>>>(Wm1, 0, 1024, feat, 1024LL * Nsz, Nsz,
        hm, 512LL * Nsz, Nsz, 512, 1024, nullptr);
    fc_stats_k<<<512, 256, 0, stream>>>(hm, stats, 512);
    bn_lrelu_k<<<(int)(((size_t)Bsz * 512 * Nsz + 255) / 256), 256, 0, stream>>>(
        hm, stats, 512, 0, 512, 1.f / 16384.f);

    sgemm_k<0, 0><<<dim3(32, 2, Bsz), 256, 0, stream>>>(Wm2, 0, 512, hm, 512LL * Nsz, Nsz,
        logits, 70LL * Nsz, Nsz, 70, 512, nullptr);

    gumbel_onehot_k<<<(Bsz * 70) / 4, 256, 0, stream>>>(logits, un, out);
}

// Round 2
// 1998.219 us; speedup vs baseline: 1.7627x; 1.7627x over previous
//
#include <hip/hip_runtime.h>
#include <math.h>

#define Bsz 8
#define Nsz 2048
#define Ksz 8
#define NSLOPE 0.2f
#define EPSV 1e-5f

// ------------------------------------------------------------------
// Tiled fp32 SGEMM: C[b] = A @ B[b], 128x128 tile, BK=16, 8x8/thread
// (2x2 groups of 4x4 at cols tx*4 / 64+tx*4 -> 2-way LDS alias = free).
// ATRANS=0: A row-major (M x K), lda = K-stride.
// ATRANS=1: A stored (K x M) row-major (pair = prev^T @ prev).
// EPI=0: plain store. EPI=1: pair epilogue -((xx[m] - 2*acc) + xx[n]),
//        xx is per-batch (stride Nsz).
// ------------------------------------------------------------------
template <int ATRANS, int EPI>
__launch_bounds__(256) __global__
void sgemm_k(const float* __restrict__ A, long long sAb, int lda,
             const float* __restrict__ Bm, long long sBb, int ldb,
             float* __restrict__ C, long long sCb, int ldc,
             int M, int Kk, const float* __restrict__ xx)
{
    __shared__ float As[16][132];
    __shared__ float Bs[16][132];
    const int b = blockIdx.z;
    const float* Ab = A + (long long)b * sAb;
    const float* Bb = Bm + (long long)b * sBb;
    const int m0 = blockIdx.y * 128, n0 = blockIdx.x * 128;
    const int tid = threadIdx.x;
    const int tx = tid & 15, ty = tid >> 4;
    const int sr = tid >> 5;          // 0..7  (staging row)
    const int sc = (tid & 31) * 4;    // 0..124 (staging col, float4)
    const int achunk = tid & 3;       // ATRANS=0 staging: k-chunk
    const int am = tid >> 2;          // ATRANS=0 staging: row 0..63

    float acc[8][8];
#pragma unroll
    for (int i = 0; i < 8; i++)
#pragma unroll
        for (int j = 0; j < 8; j++) acc[i][j] = 0.f;

    for (int k0 = 0; k0 < Kk; k0 += 16) {
        // ---- stage A ----
        if (ATRANS) {
#pragma unroll
            for (int r2 = 0; r2 < 2; r2++) {
                int kr = sr + r2 * 8;
                int gk = k0 + kr;
                float4 v = make_float4(0.f, 0.f, 0.f, 0.f);
                if (gk < Kk) v = *(const float4*)&Ab[(long long)gk * lda + m0 + sc];
                *(float4*)&As[kr][sc] = v;
            }
        } else {
#pragma unroll
            for (int r2 = 0; r2 < 2; r2++) {
                int m = am + r2 * 64;
                int gm = m0 + m;
                int kb = k0 + achunk * 4;
                float4 v = make_float4(0.f, 0.f, 0.f, 0.f);
                if (gm < M) {
                    if (kb + 3 < Kk) {
                        v = *(const float4*)&Ab[(long long)gm * lda + kb];
                    } else {
                        float tmp[4] = {0.f, 0.f, 0.f, 0.f};
#pragma unroll
                        for (int i = 0; i < 4; i++)
                            if (kb + i < Kk) tmp[i] = Ab[(long long)gm * lda + kb + i];
                        v = make_float4(tmp[0], tmp[1], tmp[2], tmp[3]);
                    }
                }
                As[achunk * 4 + 0][m] = v.x;
                As[achunk * 4 + 1][m] = v.y;
                As[achunk * 4 + 2][m] = v.z;
                As[achunk * 4 + 3][m] = v.w;
            }
        }
        // ---- stage B ----
#pragma unroll
        for (int r2 = 0; r2 < 2; r2++) {
            int kr = sr + r2 * 8;
            int gk = k0 + kr;
            float4 v = make_float4(0.f, 0.f, 0.f, 0.f);
            if (gk < Kk) v = *(const float4*)&Bb[(long long)gk * ldb + n0 + sc];
            *(float4*)&Bs[kr][sc] = v;
        }
        __syncthreads();
#pragma unroll
        for (int kk = 0; kk < 16; kk++) {
            float4 a0 = *(const float4*)&As[kk][ty * 4];
            float4 a1 = *(const float4*)&As[kk][64 + ty * 4];
            float4 b0 = *(const float4*)&Bs[kk][tx * 4];
            float4 b1 = *(const float4*)&Bs[kk][64 + tx * 4];
            float av[8] = {a0.x, a0.y, a0.z, a0.w, a1.x, a1.y, a1.z, a1.w};
            float bw[8] = {b0.x, b0.y, b0.z, b0.w, b1.x, b1.y, b1.z, b1.w};
#pragma unroll
            for (int i = 0; i < 8; i++)
#pragma unroll
                for (int j = 0; j < 8; j++)
                    acc[i][j] = fmaf(av[i], bw[j], acc[i][j]);
        }
        __syncthreads();
    }
    // ---- epilogue ----
    float* Cb = C + (long long)b * sCb;
    const float* xxp = EPI ? (xx + (long long)b * Nsz) : xx;
#pragma unroll
    for (int ii = 0; ii < 8; ii++) {
        int gm = m0 + (ii >> 2) * 64 + ty * 4 + (ii & 3);
        if (gm >= M) continue;
        float xm = EPI ? xxp[gm] : 0.f;
#pragma unroll
        for (int cg = 0; cg < 2; cg++) {
            int gn = n0 + cg * 64 + tx * 4;
            float4 o;
            if (EPI == 1) {
                float4 xn = *(const float4*)&xxp[gn];
                o.x = -((xm - 2.f * acc[ii][cg * 4 + 0]) + xn.x);
                o.y = -((xm - 2.f * acc[ii][cg * 4 + 1]) + xn.y);
                o.z = -((xm - 2.f * acc[ii][cg * 4 + 2]) + xn.z);
                o.w = -((xm - 2.f * acc[ii][cg * 4 + 3]) + xn.w);
            } else {
                o.x = acc[ii][cg * 4 + 0];
                o.y = acc[ii][cg * 4 + 1];
                o.z = acc[ii][cg * 4 + 2];
                o.w = acc[ii][cg * 4 + 3];
            }
            *(float4*)&Cb[(long long)gm * ldc + gn] = o;
        }
    }
}

// xt[b,c,n] = x[b,n,c]
__global__ void transpose_x_k(const float* __restrict__ x, float* __restrict__ xt)
{
    int t = blockIdx.x * 256 + threadIdx.x;
    if (t >= Bsz * Nsz) return;
    int n = t & (Nsz - 1), b = t >> 11;
#pragma unroll
    for (int c = 0; c < 3; c++)
        xt[((size_t)b * 3 + c) * Nsz + n] = x[((size_t)b * Nsz + n) * 3 + c];
}

// wc rows [0,O): W[:, :C];  rows [O,2O): W[:, C:] - W[:, :C]
__global__ void prep_w_k(const float* __restrict__ W, float* __restrict__ wc, int O, int C)
{
    int t = blockIdx.x * 256 + threadIdx.x;
    if (t >= O * C) return;
    int oo = t / C, c = t % C;
    float a = W[(size_t)oo * 2 * C + c];
    float b2 = W[(size_t)oo * 2 * C + C + c];
    wc[(size_t)oo * C + c] = a;
    wc[(size_t)(O + oo) * C + c] = b2 - a;
}

// xx[b,n] = sum_c prev[b,c,n]^2 ; prev per-b stride 960*N (inside cat)
__global__ void compute_xx_k(const float* __restrict__ prev, float* __restrict__ xx, int C)
{
    int t = blockIdx.x * 256 + threadIdx.x;
    if (t >= Bsz * Nsz) return;
    int n = t & (Nsz - 1), b = t >> 11;
    const float* p = prev + (size_t)b * 960 * Nsz + n;
    float s = 0.f;
    for (int c = 0; c < C; c++) { float v = p[(size_t)c * Nsz]; s = fmaf(v, v, s); }
    xx[t] = s;
}

__device__ __forceinline__ unsigned long long shfl_xor64(unsigned long long x, int off)
{
    unsigned lo = __shfl_xor((unsigned)x, off, 64);
    unsigned hi = __shfl_xor((unsigned)(x >> 32), off, 64);
    return ((unsigned long long)hi << 32) | lo;
}

// top-8 per row: single scan, per-lane sorted top-8 of packed keys, then
// 8-round cross-lane merge. key = (ord(v)<<32) | (0xFFFFFFFF - idx):
// larger value wins; equal value -> lower idx wins (JAX top_k semantics).
__global__ void topk8_k(const float* __restrict__ pair, int* __restrict__ idxo)
{
    int lane = threadIdx.x & 63;
    int row = blockIdx.x * 4 + (threadIdx.x >> 6);
    const float* pr = pair + (size_t)row * Nsz;
    unsigned long long t[8] = {0, 0, 0, 0, 0, 0, 0, 0};
    for (int m = lane; m < Nsz; m += 64) {
        float v = pr[m];
        unsigned u = __float_as_uint(v);
        u = (u & 0x80000000u) ? ~u : (u | 0x80000000u);
        unsigned long long key = ((unsigned long long)u << 32) | (0xFFFFFFFFu - (unsigned)m);
#pragma unroll
        for (int j = 7; j >= 1; --j)
            t[j] = (key > t[j - 1]) ? t[j - 1] : ((key > t[j]) ? key : t[j]);
        t[0] = (key > t[0]) ? key : t[0];
    }
    int* op = idxo + (size_t)row * 8;
#pragma unroll
    for (int r = 0; r < 8; r++) {
        unsigned long long best = t[0];
#pragma unroll
        for (int off = 32; off; off >>= 1) {
            unsigned long long o = shfl_xor64(best, off);
            if (o > best) best = o;
        }
        bool own = (t[0] == best);
#pragma unroll
        for (int j = 0; j < 7; j++) t[j] = own ? t[j + 1] : t[j];
        t[7] = own ? 0ull : t[7];
        if (lane == 0) op[r] = (int)(0xFFFFFFFFu - (unsigned)(best & 0xFFFFFFFFull));
    }
}

// h[b,o,n,k] = P[b,o,idx[b,n,k]] + Q[b,o,n]; writes max_k h into cat; partial sums of h,h^2.
// block = (64,4); grid = (N/64, O/4, B). part layout: [o][b][blk]{s1,s2}
__global__ void gather_pool_k(const float* __restrict__ R, const int* __restrict__ idx,
                              float* __restrict__ cat, float* __restrict__ part,
                              int O, int catOff)
{
    int lane = threadIdx.x;
    int os = threadIdx.y;
    int n = blockIdx.x * 64 + lane;
    int o = blockIdx.y * 4 + os;
    int b = blockIdx.z;
    const float* P = R + ((size_t)b * 2 * O + o) * Nsz;
    const float* Q = P + (size_t)O * Nsz;
    const int* id = idx + ((size_t)b * Nsz + n) * 8;
    float q = Q[n];
    float hmax = -INFINITY, s1 = 0.f, s2 = 0.f;
#pragma unroll
    for (int k = 0; k < 8; k++) {
        float h = P[id[k]] + q;
        hmax = fmaxf(hmax, h);
        s1 += h;
        s2 += h * h;
    }
    cat[((size_t)b * 960 + catOff + o) * Nsz + n] = hmax;
#pragma unroll
    for (int off = 32; off; off >>= 1) { s1 += __shfl_xor(s1, off, 64); s2 += __shfl_xor(s2, off, 64); }
    if (lane == 0) {
        size_t pi = ((size_t)o * Bsz + b) * 32 + blockIdx.x;
        part[pi * 2] = s1;
        part[pi * 2 + 1] = s2;
    }
}

// reduce 256 partials per channel -> stats[2o]=sum, stats[2o+1]=sumsq (deterministic)
__global__ void stats_reduce_k(const float* __restrict__ part, float* __restrict__ stats)
{
    int o2 = blockIdx.x;
    int t = threadIdx.x;
    float s1 = part[((size_t)o2 * 256 + t) * 2];
    float s2 = part[((size_t)o2 * 256 + t) * 2 + 1];
#pragma unroll
    for (int off = 32; off; off >>= 1) { s1 += __shfl_xor(s1, off, 64); s2 += __shfl_xor(s2, off, 64); }
    __shared__ float sh[8];
    int w = t >> 6;
    if ((t & 63) == 0) { sh[w] = s1; sh[4 + w] = s2; }
    __syncthreads();
    if (t == 0) {
        stats[2 * o2] = sh[0] + sh[1] + sh[2] + sh[3];
        stats[2 * o2 + 1] = sh[4] + sh[5] + sh[6] + sh[7];
    }
}

// per-channel stats over (B,N) for fc tensors (B,O,N), deterministic
__global__ void fc_stats_k(const float* __restrict__ buf, float* __restrict__ stats, int O)
{
    int oo = blockIdx.x;
    int t = threadIdx.x;
    float s1 = 0.f, s2 = 0.f;
    for (int i = t; i < Bsz * Nsz; i += 256) {
        int b = i >> 11, n = i & (Nsz - 1);
        float v = buf[((size_t)b * O + oo) * Nsz + n];
        s1 += v; s2 += v * v;
    }
#pragma unroll
    for (int off = 32; off; off >>= 1) { s1 += __shfl_xor(s1, off, 64); s2 += __shfl_xor(s2, off, 64); }
    __shared__ float sh[8];
    int w = t >> 6;
    if ((t & 63) == 0) { sh[w] = s1; sh[4 + w] = s2; }
    __syncthreads();
    if (t == 0) {
        stats[2 * oo] = sh[0] + sh[1] + sh[2] + sh[3];
        stats[2 * oo + 1] = sh[4] + sh[5] + sh[6] + sh[7];
    }
}

// in-place lrelu((x - mean)/sqrt(var+eps)) over (B,O,N) slice of buf
__global__ void bn_lrelu_k(float* __restrict__ buf, const float* __restrict__ stats,
                           int Ctot, int off, int O, float invCnt)
{
    size_t t = (size_t)blockIdx.x * 256 + threadIdx.x;
    size_t total = (size_t)Bsz * O * Nsz;
    if (t >= total) return;
    int n = (int)(t & (Nsz - 1));
    size_t t2 = t >> 11;
    int oo = (int)(t2 % O);
    int b = (int)(t2 / O);
    float mean = stats[2 * oo] * invCnt;
    float var = stats[2 * oo + 1] * invCnt - mean * mean;
    float* p = buf + ((size_t)b * Ctot + off + oo) * Nsz + n;
    float v = (*p - mean) / sqrtf(var + EPSV);
    *p = v >= 0.f ? v : NSLOPE * v;
}

// argmax_n(logits + gumbel(u)) per (b,o) row; exact one-hot to out (70,B,N,1)
__global__ void gumbel_onehot_k(const float* __restrict__ logits, const float* __restrict__ u,
                                float* __restrict__ out)
{
    int lane = threadIdx.x & 63;
    int wv = threadIdx.x >> 6;
    int row = blockIdx.x * 4 + wv;      // row = b*70 + o
    int b = row / 70, oo = row % 70;
    const float* L = logits + (size_t)row * Nsz;
    const float* U = u + (size_t)row * Nsz;
    float bv = -INFINITY; int bi = 0x7fffffff;
    for (int n = lane; n < Nsz; n += 64) {
        float g = -logf(-logf(U[n]));
        float z = L[n] + g;
        if (z > bv) { bv = z; bi = n; }
    }
#pragma unroll
    for (int off = 32; off; off >>= 1) {
        float ov = __shfl_xor(bv, off, 64);
        int oi = __shfl_xor(bi, off, 64);
        if (ov > bv || (ov == bv && oi < bi)) { bv = ov; bi = oi; }
    }
    float* Or = out + ((size_t)oo * Bsz + b) * Nsz;
    for (int n = lane; n < Nsz; n += 64) Or[n] = (n == bi) ? 1.f : 0.f;
}

extern "C" void kernel_launch(void* const* d_in, const int* in_sizes, int n_in,
                              void* d_out, int out_size, void* d_ws, size_t ws_size,
                              hipStream_t stream)
{
    (void)in_sizes; (void)n_in; (void)out_size; (void)ws_size;
    const float* x   = (const float*)d_in[0];
    const int*   sn  = (const int*)d_in[1];
    const float* un  = (const float*)d_in[2];
    const float* W0  = (const float*)d_in[3];
    const float* W1  = (const float*)d_in[4];
    const float* W2  = (const float*)d_in[5];
    const float* W3  = (const float*)d_in[6];
    const float* W4  = (const float*)d_in[7];
    const float* Wm1 = (const float*)d_in[8];
    const float* Wm2 = (const float*)d_in[9];
    float* out = (float*)d_out;

    float* ws = (float*)d_ws;
    size_t o = 0;
    float* cat  = ws + o; o += (size_t)Bsz * 960 * Nsz;   // 62.9 MB: out0..out3 concat
    float* Rbuf = ws + o; o += (size_t)Bsz * 1024 * Nsz;  // 67 MB: P/Q stack; pair x4; feat
    float* logits = ws + o; o += (size_t)Bsz * 70 * Nsz;  // 4.6 MB
    float* xt   = ws + o; o += (size_t)Bsz * 3 * Nsz;
    float* xxb  = ws + o; o += (size_t)Bsz * Nsz;
    float* wcat = ws + o; o += (size_t)1024 * 256;
    float* part = ws + o; o += (size_t)1024 * 256 * 2;
    float* stats= ws + o; o += 2048;
    int* idxb   = (int*)(ws + o); o += (size_t)Bsz * Nsz * Ksz;
    float* feat = Rbuf;  // alias: R dead after L4 gather
    float* hm   = cat;   // alias: cat dead after W4 gemm

    transpose_x_k<<<(Bsz * Nsz + 255) / 256, 256, 0, stream>>>(x, xt);

    // ---- edge layer 1 (C=3, O=64, idx = start_neighs) ----
    prep_w_k<<<1, 256, 0, stream>>>(W0, wcat, 64, 3);
    sgemm_k<0, 0><<<dim3(16, 1, Bsz), 256, 0, stream>>>(wcat, 0, 3, xt, 3LL * Nsz, Nsz,
                                                        Rbuf, 2LL * 64 * Nsz, Nsz, 128, 3, nullptr);
    gather_pool_k<<<dim3(32, 16, Bsz), dim3(64, 4), 0, stream>>>(Rbuf, sn, cat, part, 64, 0);
    stats_reduce_k<<<64, 256, 0, stream>>>(part, stats);
    bn_lrelu_k<<<(int)(((size_t)Bsz * 64 * Nsz + 255) / 256), 256, 0, stream>>>(
        cat, stats, 960, 0, 64, 1.f / 131072.f);

    // ---- edge layers 2..4 with knn rebuild (pair batched 4 at a time in Rbuf) ----
    struct LayerDesc { const float* W; int C; int O; int prevOff; int catOff; };
    LayerDesc L[3] = {
        { W1, 64, 128, 0, 64 },
        { W2, 128, 256, 64, 192 },
        { W3, 256, 512, 192, 448 },
    };
    for (int li = 0; li < 3; li++) {
        int C = L[li].C, O = L[li].O;
        const float* prev = cat + (size_t)L[li].prevOff * Nsz;
        compute_xx_k<<<(Bsz * Nsz + 255) / 256, 256, 0, stream>>>(prev, xxb, C);
        for (int ch = 0; ch < 2; ch++) {
            const float* pch = prev + (size_t)ch * 4 * 960 * Nsz;
            sgemm_k<1, 1><<<dim3(16, 16, 4), 256, 0, stream>>>(pch, 960LL * Nsz, Nsz,
                pch, 960LL * Nsz, Nsz,
                Rbuf, (long long)Nsz * Nsz, Nsz, Nsz, C, xxb + (size_t)ch * 4 * Nsz);
            topk8_k<<<4 * Nsz / 4, 256, 0, stream>>>(Rbuf, idxb + (size_t)ch * 4 * Nsz * Ksz);
        }
        prep_w_k<<<(O * C + 255) / 256, 256, 0, stream>>>(L[li].W, wcat, O, C);
        sgemm_k<0, 0><<<dim3(16, 2 * O / 128, Bsz), 256, 0, stream>>>(wcat, 0, C, prev, 960LL * Nsz, Nsz,
            Rbuf, 2LL * O * Nsz, Nsz, 2 * O, C, nullptr);
        gather_pool_k<<<dim3(32, O / 4, Bsz), dim3(64, 4), 0, stream>>>(Rbuf, idxb, cat, part, O, L[li].catOff);
        stats_reduce_k<<<O, 256, 0, stream>>>(part, stats);
        bn_lrelu_k<<<(int)(((size_t)Bsz * O * Nsz + 255) / 256), 256, 0, stream>>>(
            cat, stats, 960, L[li].catOff, O, 1.f / 131072.f);
    }

    // ---- fc head ----
    sgemm_k<0, 0><<<dim3(16, 8, Bsz), 256, 0, stream>>>(W4, 0, 960, cat, 960LL * Nsz, Nsz,
        feat, 1024LL * Nsz, Nsz, 1024, 960, nullptr);
    fc_stats_k<<<1024, 256, 0, stream>>>(feat, stats, 1024);
    bn_lrelu_k<<<(int)(((size_t)Bsz * 1024 * Nsz + 255) / 256), 256, 0, stream>>>(
        feat, stats, 1024, 0, 1024, 1.f / 16384.f);

    sgemm_k<0, 0><<<dim3(16, 4, Bsz), 256, 0, stream>>>(Wm1, 0, 1024, feat, 1024LL * Nsz, Nsz,
        hm, 512LL * Nsz, Nsz, 512, 1024, nullptr);
    fc_stats_k<<<512, 256, 0, stream>>>(hm, stats, 512);
    bn_lrelu_k<<<(int)(((size_t)Bsz * 512 * Nsz + 255) / 256), 256, 0, stream>>>(
        hm, stats, 512, 0, 512, 1.f / 16384.f);

    sgemm_k<0, 0><<<dim3(16, 1, Bsz), 256, 0, stream>>>(Wm2, 0, 512, hm, 512LL * Nsz, Nsz,
        logits, 70LL * Nsz, Nsz, 70, 512, nullptr);

    gumbel_onehot_k<<<(Bsz * 70) / 4, 256, 0, stream>>>(logits, un, out);
}

// Round 3
// 1391.212 us; speedup vs baseline: 2.5317x; 1.4363x over previous
//
#include <hip/hip_runtime.h>
#include <math.h>

#define Bsz 8
#define Nsz 2048
#define Ksz 8
#define NSLOPE 0.2f
#define EPSV 1e-5f
#define LOSCALE 2048.0f
#define INV_LOSCALE (1.0f / 2048.0f)

typedef _Float16 half8 __attribute__((ext_vector_type(8)));
typedef float floatx4 __attribute__((ext_vector_type(4)));

__device__ __forceinline__ void glds16(const _Float16* g, _Float16* l)
{
    __builtin_amdgcn_global_load_lds(
        (const __attribute__((address_space(1))) unsigned int*)g,
        (__attribute__((address_space(3))) unsigned int*)l, 16, 0, 0);
}

__device__ __forceinline__ void split2(float v, _Float16& h, _Float16& l)
{
    _Float16 hh = (_Float16)v;
    h = hh;
    l = (_Float16)((v - (float)hh) * LOSCALE);
}

// ------------------------------------------------------------------
// fp16-split MFMA GEMM: C[b][m][n] = sum_k A[m][k]*Bt[n][k]  (A.Bt)
// A planes [M][K] k-contig (row stride lda elems), Bt planes [N][K]
// (row stride ldb). Split: v = hi + lo/2048. Dual accumulators:
// acc_h = sum ah*bh ; acc_m = sum (ah*bl + al*bh)  [bl,al pre-scaled x2048]
// final C = acc_h + acc_m/2048. EPI=1: pair epilogue with xx.
// Tile 128x128, BK=32, 4 waves each 64x64 (4x4 frags of 16x16x32_f16).
// ------------------------------------------------------------------
template <int EPI>
__launch_bounds__(256) __global__
void hgemm_k(const _Float16* __restrict__ Ahi, const _Float16* __restrict__ Alo,
             long long sAb, int lda,
             const _Float16* __restrict__ Bhi, const _Float16* __restrict__ Blo,
             long long sBb, int ldb,
             float* __restrict__ C, long long sCb, int ldc,
             int Mreal, int Kk, const float* __restrict__ xx)
{
    __shared__ _Float16 sm[16384];   // Ahi[0,4096) Alo[4096) Bhi[8192) Blo[12288)
    const int b = blockIdx.z;
    const int m0 = blockIdx.y * 128, n0 = blockIdx.x * 128;
    const int tid = threadIdx.x;
    const int w = tid >> 6, lane = tid & 63;
    const int quad = lane >> 4, r16 = lane & 15;
    const int wm = (w >> 1) * 64, wn = (w & 1) * 64;

    const _Float16* Ah = Ahi + (long long)b * sAb;
    const _Float16* Al = Alo + (long long)b * sAb;
    const _Float16* Bh = Bhi + (long long)b * sBb;
    const _Float16* Bl = Blo + (long long)b * sBb;

    floatx4 acc_h[4][4], acc_m[4][4];
#pragma unroll
    for (int i = 0; i < 4; i++)
#pragma unroll
        for (int j = 0; j < 4; j++) {
            acc_h[i][j] = (floatx4){0.f, 0.f, 0.f, 0.f};
            acc_m[i][j] = (floatx4){0.f, 0.f, 0.f, 0.f};
        }

    for (int k0 = 0; k0 < Kk; k0 += 32) {
#pragma unroll
        for (int q = 0; q < 2; q++) {
            int idx = q * 256 + tid;          // 0..511
            int row = idx >> 2;               // 0..127
            int seg = (idx & 3) * 8;          // elem offset in 32-elem chunk
            long long aoff = (long long)(m0 + row) * lda + k0 + seg;
            long long boff = (long long)(n0 + row) * ldb + k0 + seg;
            glds16(Ah + aoff, &sm[idx * 8]);
            glds16(Al + aoff, &sm[4096 + idx * 8]);
            glds16(Bh + boff, &sm[8192 + idx * 8]);
            glds16(Bl + boff, &sm[12288 + idx * 8]);
        }
        __syncthreads();

        half8 ah[4], al[4];
#pragma unroll
        for (int i = 0; i < 4; i++) {
            int off = (wm + i * 16 + r16) * 32 + quad * 8;
            ah[i] = *(const half8*)&sm[off];
            al[i] = *(const half8*)&sm[4096 + off];
        }
#pragma unroll
        for (int j = 0; j < 4; j++) {
            int off = (wn + j * 16 + r16) * 32 + quad * 8;
            half8 bh = *(const half8*)&sm[8192 + off];
            half8 bl = *(const half8*)&sm[12288 + off];
#pragma unroll
            for (int i = 0; i < 4; i++) {
                acc_h[i][j] = __builtin_amdgcn_mfma_f32_16x16x32_f16(ah[i], bh, acc_h[i][j], 0, 0, 0);
                acc_m[i][j] = __builtin_amdgcn_mfma_f32_16x16x32_f16(ah[i], bl, acc_m[i][j], 0, 0, 0);
                acc_m[i][j] = __builtin_amdgcn_mfma_f32_16x16x32_f16(al[i], bh, acc_m[i][j], 0, 0, 0);
            }
        }
        __syncthreads();
    }

    float* Cb = C + (long long)b * sCb;
    const float* xxp = EPI ? (xx + (long long)b * Nsz) : xx;
#pragma unroll
    for (int i = 0; i < 4; i++) {
#pragma unroll
        for (int r = 0; r < 4; r++) {
            int gm = m0 + wm + i * 16 + quad * 4 + r;
            if (gm >= Mreal) continue;
            float xm = EPI ? xxp[gm] : 0.f;
#pragma unroll
            for (int j = 0; j < 4; j++) {
                int gn = n0 + wn + j * 16 + r16;
                float v = acc_h[i][j][r] + acc_m[i][j][r] * INV_LOSCALE;
                if (EPI == 1) v = -((xm - 2.f * v) + xxp[gn]);
                Cb[(long long)gm * ldc + gn] = v;
            }
        }
    }
}

// ------------------------------------------------------------------
// fp32 SGEMM (layer-1 only, K=3): C[b] = A @ B[b], 64x64 tile.
// ------------------------------------------------------------------
__launch_bounds__(256) __global__
void sgemm_k(const float* __restrict__ A, int lda,
             const float* __restrict__ Bm, long long sBb, int ldb,
             float* __restrict__ C, long long sCb, int ldc,
             int M, int Kk)
{
    __shared__ float As[16][64];
    __shared__ float Bs[16][64];
    const int b = blockIdx.z;
    const float* Bb = Bm + (long long)b * sBb;
    const int m0 = blockIdx.y * 64, n0 = blockIdx.x * 64;
    const int tid = threadIdx.x;
    const int am = tid >> 2, ak = (tid & 3) * 4;
    const int bk = tid >> 6, bn = tid & 63;
    const int tx = tid & 15, ty = tid >> 4;
    float acc[4][4] = {};
    for (int k0 = 0; k0 < Kk; k0 += 16) {
#pragma unroll
        for (int i = 0; i < 4; i++) {
            int gk = k0 + ak + i;
            int gm = m0 + am;
            As[ak + i][am] = (gk < Kk && gm < M) ? A[(long long)gm * lda + gk] : 0.f;
        }
#pragma unroll
        for (int i = 0; i < 4; i++) {
            int kk = bk + i * 4;
            int gk = k0 + kk;
            Bs[kk][bn] = (gk < Kk) ? Bb[(long long)gk * ldb + (n0 + bn)] : 0.f;
        }
        __syncthreads();
#pragma unroll
        for (int kk = 0; kk < 16; kk++) {
            float a[4], bb2[4];
#pragma unroll
            for (int i = 0; i < 4; i++) a[i] = As[kk][ty * 4 + i];
#pragma unroll
            for (int j = 0; j < 4; j++) bb2[j] = Bs[kk][tx * 4 + j];
#pragma unroll
            for (int i = 0; i < 4; i++)
#pragma unroll
                for (int j = 0; j < 4; j++)
                    acc[i][j] = fmaf(a[i], bb2[j], acc[i][j]);
        }
        __syncthreads();
    }
    float* Cb = C + (long long)b * sCb;
#pragma unroll
    for (int i = 0; i < 4; i++) {
        int gm = m0 + ty * 4 + i;
        if (gm >= M) continue;
#pragma unroll
        for (int j = 0; j < 4; j++)
            Cb[(long long)gm * ldc + n0 + tx * 4 + j] = acc[i][j];
    }
}

// xt[b,c,n] = x[b,n,c]
__global__ void transpose_x_k(const float* __restrict__ x, float* __restrict__ xt)
{
    int t = blockIdx.x * 256 + threadIdx.x;
    if (t >= Bsz * Nsz) return;
    int n = t & (Nsz - 1), b = t >> 11;
#pragma unroll
    for (int c = 0; c < 3; c++)
        xt[((size_t)b * 3 + c) * Nsz + n] = x[((size_t)b * Nsz + n) * 3 + c];
}

// layer-1 fp32 wcat: rows [0,O): W[:, :C]; rows [O,2O): W[:, C:] - W[:, :C]
__global__ void prep_w_k(const float* __restrict__ W, float* __restrict__ wc, int O, int C)
{
    int t = blockIdx.x * 256 + threadIdx.x;
    if (t >= O * C) return;
    int oo = t / C, c = t % C;
    float a = W[(size_t)oo * 2 * C + c];
    float b2 = W[(size_t)oo * 2 * C + C + c];
    wc[(size_t)oo * C + c] = a;
    wc[(size_t)(O + oo) * C + c] = b2 - a;
}

// plain weight split with row padding (rows >= M -> 0)
__global__ void split_w_k(const float* __restrict__ W, _Float16* __restrict__ wh,
                          _Float16* __restrict__ wl, int M, int Mpad, int Kk)
{
    int t = blockIdx.x * 256 + threadIdx.x;
    if (t >= Mpad * Kk) return;
    int oo = t / Kk, c = t - oo * Kk;
    float v = (oo < M) ? W[(size_t)oo * Kk + c] : 0.f;
    split2(v, wh[t], wl[t]);
}

// edge weight split: rows [0,O): A = W[:, :C]; rows [O,2O): B-A
__global__ void split_w_edge_k(const float* __restrict__ W, _Float16* __restrict__ wh,
                               _Float16* __restrict__ wl, int O, int C)
{
    int t = blockIdx.x * 256 + threadIdx.x;
    if (t >= 2 * O * C) return;
    int oo = t / C, c = t - oo * C;
    float v;
    if (oo < O) v = W[(size_t)oo * 2 * C + c];
    else { int o2 = oo - O; v = W[(size_t)o2 * 2 * C + C + c] - W[(size_t)o2 * 2 * C + c]; }
    split2(v, wh[t], wl[t]);
}

// xx[b,n] = sum_c v^2 with v from planes, dropping lo^2 (matches GEMM's form)
__global__ void xx_planes_k(const _Float16* __restrict__ catA, const _Float16* __restrict__ catB,
                            float* __restrict__ xx, int off, int C)
{
    int t = blockIdx.x * 256 + threadIdx.x;
    if (t >= Bsz * Nsz) return;
    int n = t & (Nsz - 1), b = t >> 11;
    size_t base = ((size_t)b * Nsz + n) * 1024 + off;
    float s = 0.f;
    for (int c8 = 0; c8 < C / 8; c8++) {
        half8 h = *(const half8*)&catA[base + c8 * 8];
        half8 l = *(const half8*)&catB[base + c8 * 8];
#pragma unroll
        for (int e = 0; e < 8; e++) {
            float vh = (float)h[e];
            float vl = (float)l[e] * INV_LOSCALE;
            s = fmaf(vh, vh, s);
            s = fmaf(2.f * vh, vl, s);
        }
    }
    xx[t] = s;
}

__device__ __forceinline__ unsigned long long shfl_xor64(unsigned long long x, int off)
{
    unsigned lo = __shfl_xor((unsigned)x, off, 64);
    unsigned hi = __shfl_xor((unsigned)(x >> 32), off, 64);
    return ((unsigned long long)hi << 32) | lo;
}

// top-8 per row (JAX semantics: value desc, ties -> lower index)
__global__ void topk8_k(const float* __restrict__ pair, int* __restrict__ idxo)
{
    int lane = threadIdx.x & 63;
    int row = blockIdx.x * 4 + (threadIdx.x >> 6);
    const float* pr = pair + (size_t)row * Nsz;
    unsigned long long t[8] = {0, 0, 0, 0, 0, 0, 0, 0};
    for (int m = lane; m < Nsz; m += 64) {
        float v = pr[m];
        unsigned u = __float_as_uint(v);
        u = (u & 0x80000000u) ? ~u : (u | 0x80000000u);
        unsigned long long key = ((unsigned long long)u << 32) | (0xFFFFFFFFu - (unsigned)m);
#pragma unroll
        for (int j = 7; j >= 1; --j)
            t[j] = (key > t[j - 1]) ? t[j - 1] : ((key > t[j]) ? key : t[j]);
        t[0] = (key > t[0]) ? key : t[0];
    }
    int* op = idxo + (size_t)row * 8;
#pragma unroll
    for (int r = 0; r < 8; r++) {
        unsigned long long best = t[0];
#pragma unroll
        for (int off = 32; off; off >>= 1) {
            unsigned long long o = shfl_xor64(best, off);
            if (o > best) best = o;
        }
        bool own = (t[0] == best);
#pragma unroll
        for (int j = 0; j < 7; j++) t[j] = own ? t[j + 1] : t[j];
        t[7] = own ? 0ull : t[7];
        if (lane == 0) op[r] = (int)(0xFFFFFFFFu - (unsigned)(best & 0xFFFFFFFFull));
    }
}

// gather + max-pool + stats + transpose + split: R[b][2O][n] -> catT planes [b][n][off+o]
// grid (N/64, O/64, B), block 256. part[(o*8+b)*32 + blkx] = {s1,s2}
__global__ void gather_pool_t_k(const float* __restrict__ R, const int* __restrict__ idx,
                                _Float16* __restrict__ catA, _Float16* __restrict__ catB,
                                float* __restrict__ part, int O, int off)
{
    __shared__ float tile[64][65];
    const int tid = threadIdx.x;
    const int lane = tid & 63, w = tid >> 6;
    const int n0 = blockIdx.x * 64, o0 = blockIdx.y * 64, b = blockIdx.z;
    const int n = n0 + lane;

    int id[8];
    {
        const int* ip = idx + ((size_t)b * Nsz + n) * 8;
#pragma unroll
        for (int k = 0; k < 8; k++) id[k] = ip[k];
    }
    const float* Rb = R + (size_t)b * 2 * O * Nsz;
#pragma unroll
    for (int i = 0; i < 16; i++) {
        int o_l = w + i * 4;
        int o = o0 + o_l;
        const float* P = Rb + (size_t)o * Nsz;
        float q = Rb[(size_t)(O + o) * Nsz + n];
        float hmax = -INFINITY, s1 = 0.f, s2 = 0.f;
#pragma unroll
        for (int k = 0; k < 8; k++) {
            float h = P[id[k]] + q;
            hmax = fmaxf(hmax, h);
            s1 += h;
            s2 += h * h;
        }
        tile[o_l][lane] = hmax;
#pragma unroll
        for (int offs = 32; offs; offs >>= 1) {
            s1 += __shfl_xor(s1, offs, 64);
            s2 += __shfl_xor(s2, offs, 64);
        }
        if (lane == 0) {
            size_t pi = ((size_t)o * Bsz + b) * 32 + blockIdx.x;
            part[pi * 2] = s1;
            part[pi * 2 + 1] = s2;
        }
    }
    __syncthreads();
    // transposed write: n_l = tid>>2, quad = tid&3 -> 16 o's
    int n_l = tid >> 2, quad = tid & 3;
    half8 h0, h1, l0, l1;
#pragma unroll
    for (int e = 0; e < 8; e++) {
        _Float16 hh, ll;
        split2(tile[quad * 16 + e][n_l], hh, ll);
        h0[e] = hh; l0[e] = ll;
        split2(tile[quad * 16 + 8 + e][n_l], hh, ll);
        h1[e] = hh; l1[e] = ll;
    }
    size_t dst = ((size_t)b * Nsz + n0 + n_l) * 1024 + off + o0 + quad * 16;
    *(half8*)&catA[dst] = h0;
    *(half8*)&catA[dst + 8] = h1;
    *(half8*)&catB[dst] = l0;
    *(half8*)&catB[dst + 8] = l1;
}

// reduce 256 partials per channel -> stats[2o]=sum, stats[2o+1]=sumsq
__global__ void stats_reduce_k(const float* __restrict__ part, float* __restrict__ stats)
{
    int o2 = blockIdx.x;
    int t = threadIdx.x;
    float s1 = part[((size_t)o2 * 256 + t) * 2];
    float s2 = part[((size_t)o2 * 256 + t) * 2 + 1];
#pragma unroll
    for (int off = 32; off; off >>= 1) { s1 += __shfl_xor(s1, off, 64); s2 += __shfl_xor(s2, off, 64); }
    __shared__ float sh[8];
    int w = t >> 6;
    if ((t & 63) == 0) { sh[w] = s1; sh[4 + w] = s2; }
    __syncthreads();
    if (t == 0) {
        stats[2 * o2] = sh[0] + sh[1] + sh[2] + sh[3];
        stats[2 * o2 + 1] = sh[4] + sh[5] + sh[6] + sh[7];
    }
}

// per-channel stats over (B,N) for fc tensors (B,O,N) fp32
__global__ void fc_stats_k(const float* __restrict__ buf, float* __restrict__ stats, int O)
{
    int oo = blockIdx.x;
    int t = threadIdx.x;
    float s1 = 0.f, s2 = 0.f;
    for (int i = t; i < Bsz * Nsz; i += 256) {
        int b = i >> 11, n = i & (Nsz - 1);
        float v = buf[((size_t)b * O + oo) * Nsz + n];
        s1 += v; s2 += v * v;
    }
#pragma unroll
    for (int off = 32; off; off >>= 1) { s1 += __shfl_xor(s1, off, 64); s2 += __shfl_xor(s2, off, 64); }
    __shared__ float sh[8];
    int w = t >> 6;
    if ((t & 63) == 0) { sh[w] = s1; sh[4 + w] = s2; }
    __syncthreads();
    if (t == 0) {
        stats[2 * oo] = sh[0] + sh[1] + sh[2] + sh[3];
        stats[2 * oo + 1] = sh[4] + sh[5] + sh[6] + sh[7];
    }
}

// in-place BN+lrelu on catT plane slice cols [off, off+O)
__global__ void bn_t_k(_Float16* __restrict__ catA, _Float16* __restrict__ catB,
                       const float* __restrict__ stats, int off, int O, float invCnt)
{
    int per_n = O / 8;
    size_t t = (size_t)blockIdx.x * 256 + threadIdx.x;
    if (t >= (size_t)Bsz * Nsz * per_n) return;
    int c8 = (int)(t % per_n);
    size_t rest = t / per_n;
    int n = (int)(rest & (Nsz - 1));
    int b = (int)(rest >> 11);
    size_t base = ((size_t)b * Nsz + n) * 1024 + off + c8 * 8;
    half8 h = *(const half8*)&catA[base];
    half8 l = *(const half8*)&catB[base];
    half8 ho, lo;
#pragma unroll
    for (int e = 0; e < 8; e++) {
        int oo = c8 * 8 + e;
        float mean = stats[2 * oo] * invCnt;
        float var = stats[2 * oo + 1] * invCnt - mean * mean;
        float v = (float)h[e] + (float)l[e] * INV_LOSCALE;
        float z = (v - mean) / sqrtf(var + EPSV);
        z = z >= 0.f ? z : NSLOPE * z;
        _Float16 hh, ll;
        split2(z, hh, ll);
        ho[e] = hh; lo[e] = ll;
    }
    *(half8*)&catA[base] = ho;
    *(half8*)&catB[base] = lo;
}

// fp32 [b][O][n] + BN + lrelu -> transposed planes [b][n][o] (row stride ldt)
// grid (N/64, O/64, B), block 256
__global__ void bn_split_t_k(const float* __restrict__ src, const float* __restrict__ stats,
                             _Float16* __restrict__ dA, _Float16* __restrict__ dB,
                             int O, int ldt, float invCnt)
{
    __shared__ float tile[64][65];
    const int tid = threadIdx.x;
    const int n0 = blockIdx.x * 64, o0 = blockIdx.y * 64, b = blockIdx.z;
#pragma unroll
    for (int i = 0; i < 16; i++) {
        int flat = tid + 256 * i;
        int o_l = flat >> 6, n_l = flat & 63;
        int oo = o0 + o_l;
        float mean = stats[2 * oo] * invCnt;
        float var = stats[2 * oo + 1] * invCnt - mean * mean;
        float v = src[((size_t)b * O + oo) * Nsz + n0 + n_l];
        float z = (v - mean) / sqrtf(var + EPSV);
        tile[o_l][n_l] = z >= 0.f ? z : NSLOPE * z;
    }
    __syncthreads();
    int n_l = tid >> 2, quad = tid & 3;
    half8 h0, h1, l0, l1;
#pragma unroll
    for (int e = 0; e < 8; e++) {
        _Float16 hh, ll;
        split2(tile[quad * 16 + e][n_l], hh, ll);
        h0[e] = hh; l0[e] = ll;
        split2(tile[quad * 16 + 8 + e][n_l], hh, ll);
        h1[e] = hh; l1[e] = ll;
    }
    size_t dst = ((size_t)b * Nsz + n0 + n_l) * ldt + o0 + quad * 16;
    *(half8*)&dA[dst] = h0;
    *(half8*)&dA[dst + 8] = h1;
    *(half8*)&dB[dst] = l0;
    *(half8*)&dB[dst + 8] = l1;
}

// argmax_n(logits + gumbel(u)); exact one-hot to out (70,B,N,1)
__global__ void gumbel_onehot_k(const float* __restrict__ logits, const float* __restrict__ u,
                                float* __restrict__ out)
{
    int lane = threadIdx.x & 63;
    int wv = threadIdx.x >> 6;
    int row = blockIdx.x * 4 + wv;      // row = b*70 + o
    int b = row / 70, oo = row % 70;
    const float* L = logits + (size_t)row * Nsz;
    const float* U = u + (size_t)row * Nsz;
    float bv = -INFINITY; int bi = 0x7fffffff;
    for (int n = lane; n < Nsz; n += 64) {
        float g = -logf(-logf(U[n]));
        float z = L[n] + g;
        if (z > bv) { bv = z; bi = n; }
    }
#pragma unroll
    for (int off = 32; off; off >>= 1) {
        float ov = __shfl_xor(bv, off, 64);
        int oi = __shfl_xor(bi, off, 64);
        if (ov > bv || (ov == bv && oi < bi)) { bv = ov; bi = oi; }
    }
    float* Or = out + ((size_t)oo * Bsz + b) * Nsz;
    for (int n = lane; n < Nsz; n += 64) Or[n] = (n == bi) ? 1.f : 0.f;
}

extern "C" void kernel_launch(void* const* d_in, const int* in_sizes, int n_in,
                              void* d_out, int out_size, void* d_ws, size_t ws_size,
                              hipStream_t stream)
{
    (void)in_sizes; (void)n_in; (void)out_size; (void)ws_size;
    const float* x   = (const float*)d_in[0];
    const int*   sn  = (const int*)d_in[1];
    const float* un  = (const float*)d_in[2];
    const float* W0  = (const float*)d_in[3];
    const float* W1  = (const float*)d_in[4];
    const float* W2  = (const float*)d_in[5];
    const float* W3  = (const float*)d_in[6];
    const float* W4  = (const float*)d_in[7];
    const float* Wm1 = (const float*)d_in[8];
    const float* Wm2 = (const float*)d_in[9];
    float* out = (float*)d_out;

    char* ws = (char*)d_ws;
    size_t o = 0;
    _Float16* catA = (_Float16*)(ws + o); o += (size_t)Bsz * Nsz * 1024 * 2;  // 33.5 MB
    _Float16* catB = (_Float16*)(ws + o); o += (size_t)Bsz * Nsz * 1024 * 2;  // 33.5 MB
    float* R       = (float*)(ws + o);    o += (size_t)Bsz * 1024 * Nsz * 4;  // 67 MB
    _Float16* wHi  = (_Float16*)(ws + o); o += (size_t)1024 * 1024 * 2;
    _Float16* wLo  = (_Float16*)(ws + o); o += (size_t)1024 * 1024 * 2;
    float* xt      = (float*)(ws + o);    o += (size_t)Bsz * 3 * Nsz * 4;
    float* xxb     = (float*)(ws + o);    o += (size_t)Bsz * Nsz * 4;
    float* wcat32  = (float*)(ws + o);    o += 4096;
    float* part    = (float*)(ws + o);    o += (size_t)512 * Bsz * 32 * 2 * 4;
    float* stats   = (float*)(ws + o);    o += 2048 * 4;
    int* idxb      = (int*)(ws + o);      o += (size_t)Bsz * Nsz * Ksz * 4;
    float* logits  = R + (size_t)12 * 1024 * 1024;  // inside R (hm region dead by then)

    const long long catStride = (long long)Nsz * 1024;  // per-batch elems in catT

    // ---- edge layer 1 (C=3, O=64, idx = start_neighs), fp32 path ----
    transpose_x_k<<<(Bsz * Nsz + 255) / 256, 256, 0, stream>>>(x, xt);
    prep_w_k<<<1, 256, 0, stream>>>(W0, wcat32, 64, 3);
    sgemm_k<<<dim3(32, 2, Bsz), 256, 0, stream>>>(wcat32, 3, xt, 3LL * Nsz, Nsz,
                                                  R, 2LL * 64 * Nsz, Nsz, 128, 3);
    gather_pool_t_k<<<dim3(32, 1, Bsz), 256, 0, stream>>>(R, sn, catA, catB, part, 64, 0);
    stats_reduce_k<<<64, 256, 0, stream>>>(part, stats);
    bn_t_k<<<(int)(((size_t)Bsz * Nsz * 8 + 255) / 256), 256, 0, stream>>>(
        catA, catB, stats, 0, 64, 1.f / 131072.f);

    // ---- edge layers 2..4 ----
    struct LayerDesc { const float* W; int C; int O; int prevOff; int catOff; };
    LayerDesc L[3] = {
        { W1, 64, 128, 0, 64 },
        { W2, 128, 256, 64, 192 },
        { W3, 256, 512, 192, 448 },
    };
    for (int li = 0; li < 3; li++) {
        int C = L[li].C, O = L[li].O;
        int poff = L[li].prevOff;
        xx_planes_k<<<(Bsz * Nsz + 255) / 256, 256, 0, stream>>>(catA, catB, xxb, poff, C);
        // pair = prev^T prev per batch, 4 batches per chunk into R
        for (int ch = 0; ch < 2; ch++) {
            const _Float16* pA = catA + poff + (size_t)ch * 4 * catStride;
            const _Float16* pB = catB + poff + (size_t)ch * 4 * catStride;
            hgemm_k<1><<<dim3(16, 16, 4), 256, 0, stream>>>(
                pA, pB, catStride, 1024, pA, pB, catStride, 1024,
                R, (long long)Nsz * Nsz, Nsz, Nsz, C, xxb + (size_t)ch * 4 * Nsz);
            topk8_k<<<4 * Nsz / 4, 256, 0, stream>>>(R, idxb + (size_t)ch * 4 * Nsz * Ksz);
        }
        // edge GEMM: R[b][2O][n] = wsplit @ prevT
        split_w_edge_k<<<(2 * O * C + 255) / 256, 256, 0, stream>>>(L[li].W, wHi, wLo, O, C);
        hgemm_k<0><<<dim3(16, 2 * O / 128, Bsz), 256, 0, stream>>>(
            wHi, wLo, 0, C, catA + poff, catB + poff, catStride, 1024,
            R, 2LL * O * Nsz, Nsz, 2 * O, C, nullptr);
        gather_pool_t_k<<<dim3(32, O / 64, Bsz), 256, 0, stream>>>(
            R, idxb, catA, catB, part, O, L[li].catOff);
        stats_reduce_k<<<O, 256, 0, stream>>>(part, stats);
        bn_t_k<<<(int)(((size_t)Bsz * Nsz * (O / 8) + 255) / 256), 256, 0, stream>>>(
            catA, catB, stats, L[li].catOff, O, 1.f / 131072.f);
    }

    // ---- fc head ----
    // feat = W4 @ cat : [b][1024][n] fp32 in R
    split_w_k<<<(1024 * 960 + 255) / 256, 256, 0, stream>>>(W4, wHi, wLo, 1024, 1024, 960);
    hgemm_k<0><<<dim3(16, 8, Bsz), 256, 0, stream>>>(
        wHi, wLo, 0, 960, catA, catB, catStride, 1024,
        R, 1024LL * Nsz, Nsz, 1024, 960, nullptr);
    fc_stats_k<<<1024, 256, 0, stream>>>(R, stats, 1024);
    bn_split_t_k<<<dim3(32, 16, Bsz), 256, 0, stream>>>(R, stats, catA, catB, 1024, 1024,
                                                        1.f / 16384.f);
    // hm = Wm1 @ feat : [b][512][n] fp32 in R
    split_w_k<<<(512 * 1024 + 255) / 256, 256, 0, stream>>>(Wm1, wHi, wLo, 512, 512, 1024);
    hgemm_k<0><<<dim3(16, 4, Bsz), 256, 0, stream>>>(
        wHi, wLo, 0, 1024, catA, catB, catStride, 1024,
        R, 512LL * Nsz, Nsz, 512, 1024, nullptr);
    fc_stats_k<<<512, 256, 0, stream>>>(R, stats, 512);
    bn_split_t_k<<<dim3(32, 8, Bsz), 256, 0, stream>>>(R, stats, catA, catB, 512, 512,
                                                       1.f / 16384.f);
    // logits = Wm2 @ hm : [b][70][n] fp32
    split_w_k<<<(128 * 512 + 255) / 256, 256, 0, stream>>>(Wm2, wHi, wLo, 70, 128, 512);
    hgemm_k<0><<<dim3(16, 1, Bsz), 256, 0, stream>>>(
        wHi, wLo, 0, 512, catA, catB, (long long)Nsz * 512, 512,
        logits, 70LL * Nsz, Nsz, 70, 512, nullptr);

    gumbel_onehot_k<<<(Bsz * 70) / 4, 256, 0, stream>>>(logits, un, out);
}

// Round 4
// 1370.335 us; speedup vs baseline: 2.5703x; 1.0152x over previous
//
#include <hip/hip_runtime.h>
#include <math.h>

#define Bsz 8
#define Nsz 2048
#define Ksz 8
#define NSLOPE 0.2f
#define EPSV 1e-5f
#define LOSCALE 2048.0f
#define INV_LOSCALE (1.0f / 2048.0f)

typedef _Float16 half8 __attribute__((ext_vector_type(8)));
typedef float floatx4 __attribute__((ext_vector_type(4)));

// K-chunk swizzle: within each aligned 32-half K-window of row r, the 8-half
// chunk at original position p is stored at position (p + (r>>1)) & 3.
// Makes hgemm's ds_read_b128 frag reads bank-conflict-free (2-way only).
__device__ __forceinline__ int swzk(int k, int row)
{
    return (k & ~31) | ((((k >> 3) + (row >> 1)) & 3) << 3) | (k & 7);
}

__device__ __forceinline__ void glds16(const _Float16* g, _Float16* l)
{
    __builtin_amdgcn_global_load_lds(
        (const __attribute__((address_space(1))) unsigned int*)g,
        (__attribute__((address_space(3))) unsigned int*)l, 16, 0, 0);
}

__device__ __forceinline__ void split2(float v, _Float16& h, _Float16& l)
{
    _Float16 hh = (_Float16)v;
    h = hh;
    l = (_Float16)((v - (float)hh) * LOSCALE);
}

// ------------------------------------------------------------------
// fp16-split MFMA GEMM: C[b][m][n] = sum_k A[m][k]*Bt[n][k]  (A.Bt)
// Planes stored K-chunk-swizzled (swzk). Split: v = hi + lo/2048.
// acc_h = ah*bh ; acc_m = ah*bl + al*bh ; C = acc_h + acc_m/2048.
// Tile 128x128, BK=32, 4 waves each 64x64 (4x4 frags of 16x16x32_f16).
// ------------------------------------------------------------------
template <int EPI>
__launch_bounds__(256) __global__
void hgemm_k(const _Float16* __restrict__ Ahi, const _Float16* __restrict__ Alo,
             long long sAb, int lda,
             const _Float16* __restrict__ Bhi, const _Float16* __restrict__ Blo,
             long long sBb, int ldb,
             float* __restrict__ C, long long sCb, int ldc,
             int Mreal, int Kk, const float* __restrict__ xx)
{
    __shared__ _Float16 sm[16384];   // Ahi[0,4096) Alo[4096) Bhi[8192) Blo[12288)
    const int b = blockIdx.z;
    const int m0 = blockIdx.y * 128, n0 = blockIdx.x * 128;
    const int tid = threadIdx.x;
    const int w = tid >> 6, lane = tid & 63;
    const int quad = lane >> 4, r16 = lane & 15;
    const int wm = (w >> 1) * 64, wn = (w & 1) * 64;
    const int sq = (r16 >> 1) & 3;   // swizzle shift for this lane's frag rows

    const _Float16* Ah = Ahi + (long long)b * sAb;
    const _Float16* Al = Alo + (long long)b * sAb;
    const _Float16* Bh = Bhi + (long long)b * sBb;
    const _Float16* Bl = Blo + (long long)b * sBb;

    floatx4 acc_h[4][4], acc_m[4][4];
#pragma unroll
    for (int i = 0; i < 4; i++)
#pragma unroll
        for (int j = 0; j < 4; j++) {
            acc_h[i][j] = (floatx4){0.f, 0.f, 0.f, 0.f};
            acc_m[i][j] = (floatx4){0.f, 0.f, 0.f, 0.f};
        }

    const int kchunk = ((quad + sq) & 3) * 8;   // swizzled LDS chunk offset

    for (int k0 = 0; k0 < Kk; k0 += 32) {
#pragma unroll
        for (int q = 0; q < 2; q++) {
            int idx = q * 256 + tid;          // 0..511
            int row = idx >> 2;               // 0..127
            int seg = (idx & 3) * 8;          // byte-copy of swizzled window
            long long aoff = (long long)(m0 + row) * lda + k0 + seg;
            long long boff = (long long)(n0 + row) * ldb + k0 + seg;
            glds16(Ah + aoff, &sm[idx * 8]);
            glds16(Al + aoff, &sm[4096 + idx * 8]);
            glds16(Bh + boff, &sm[8192 + idx * 8]);
            glds16(Bl + boff, &sm[12288 + idx * 8]);
        }
        __syncthreads();

        half8 ah[4], al[4];
#pragma unroll
        for (int i = 0; i < 4; i++) {
            int off = (wm + i * 16 + r16) * 32 + kchunk;
            ah[i] = *(const half8*)&sm[off];
            al[i] = *(const half8*)&sm[4096 + off];
        }
#pragma unroll
        for (int j = 0; j < 4; j++) {
            int off = (wn + j * 16 + r16) * 32 + kchunk;
            half8 bh = *(const half8*)&sm[8192 + off];
            half8 bl = *(const half8*)&sm[12288 + off];
#pragma unroll
            for (int i = 0; i < 4; i++) {
                acc_h[i][j] = __builtin_amdgcn_mfma_f32_16x16x32_f16(ah[i], bh, acc_h[i][j], 0, 0, 0);
                acc_m[i][j] = __builtin_amdgcn_mfma_f32_16x16x32_f16(ah[i], bl, acc_m[i][j], 0, 0, 0);
                acc_m[i][j] = __builtin_amdgcn_mfma_f32_16x16x32_f16(al[i], bh, acc_m[i][j], 0, 0, 0);
            }
        }
        __syncthreads();
    }

    float* Cb = C + (long long)b * sCb;
    const float* xxp = EPI ? (xx + (long long)b * Nsz) : xx;
#pragma unroll
    for (int i = 0; i < 4; i++) {
#pragma unroll
        for (int r = 0; r < 4; r++) {
            int gm = m0 + wm + i * 16 + quad * 4 + r;
            if (gm >= Mreal) continue;
            float xm = EPI ? xxp[gm] : 0.f;
#pragma unroll
            for (int j = 0; j < 4; j++) {
                int gn = n0 + wn + j * 16 + r16;
                float v = acc_h[i][j][r] + acc_m[i][j][r] * INV_LOSCALE;
                if (EPI == 1) v = -((xm - 2.f * v) + xxp[gn]);
                Cb[(long long)gm * ldc + gn] = v;
            }
        }
    }
}

// ------------------------------------------------------------------
// fp32 SGEMM (layer-1 only, K=3): C[b] = A @ B[b], 64x64 tile.
// ------------------------------------------------------------------
__launch_bounds__(256) __global__
void sgemm_k(const float* __restrict__ A, int lda,
             const float* __restrict__ Bm, long long sBb, int ldb,
             float* __restrict__ C, long long sCb, int ldc,
             int M, int Kk)
{
    __shared__ float As[16][64];
    __shared__ float Bs[16][64];
    const int b = blockIdx.z;
    const float* Bb = Bm + (long long)b * sBb;
    const int m0 = blockIdx.y * 64, n0 = blockIdx.x * 64;
    const int tid = threadIdx.x;
    const int am = tid >> 2, ak = (tid & 3) * 4;
    const int bk = tid >> 6, bn = tid & 63;
    const int tx = tid & 15, ty = tid >> 4;
    float acc[4][4] = {};
    for (int k0 = 0; k0 < Kk; k0 += 16) {
#pragma unroll
        for (int i = 0; i < 4; i++) {
            int gk = k0 + ak + i;
            int gm = m0 + am;
            As[ak + i][am] = (gk < Kk && gm < M) ? A[(long long)gm * lda + gk] : 0.f;
        }
#pragma unroll
        for (int i = 0; i < 4; i++) {
            int kk = bk + i * 4;
            int gk = k0 + kk;
            Bs[kk][bn] = (gk < Kk) ? Bb[(long long)gk * ldb + (n0 + bn)] : 0.f;
        }
        __syncthreads();
#pragma unroll
        for (int kk = 0; kk < 16; kk++) {
            float a[4], bb2[4];
#pragma unroll
            for (int i = 0; i < 4; i++) a[i] = As[kk][ty * 4 + i];
#pragma unroll
            for (int j = 0; j < 4; j++) bb2[j] = Bs[kk][tx * 4 + j];
#pragma unroll
            for (int i = 0; i < 4; i++)
#pragma unroll
                for (int j = 0; j < 4; j++)
                    acc[i][j] = fmaf(a[i], bb2[j], acc[i][j]);
        }
        __syncthreads();
    }
    float* Cb = C + (long long)b * sCb;
#pragma unroll
    for (int i = 0; i < 4; i++) {
        int gm = m0 + ty * 4 + i;
        if (gm >= M) continue;
#pragma unroll
        for (int j = 0; j < 4; j++)
            Cb[(long long)gm * ldc + n0 + tx * 4 + j] = acc[i][j];
    }
}

// ------------------------------------------------------------------
// One-shot prep: xt transpose + layer-1 fp32 wcat + all weight plane
// splits (swizzled). Segment boundaries are compile-time constants.
// ------------------------------------------------------------------
#define T0 16384            // transpose_x items (b*n)
#define T1 (T0 + 192)       // prep_w32 (64*3)
#define T2 (T1 + 16384)     // W1 edge split: O=128,C=64
#define T3 (T2 + 65536)     // W2 edge: O=256,C=128
#define T4 (T3 + 262144)    // W3 edge: O=512,C=256
#define T5 (T4 + 983040)    // W4 plain: 1024x960
#define T6 (T5 + 524288)    // Wm1 plain: 512x1024
#define T7 (T6 + 65536)     // Wm2 plain padded: 128x512 (M=70)
#define WOFF_E1 0
#define WOFF_E2 16384
#define WOFF_E3 81920
#define WOFF_W4 344064
#define WOFF_M1 1327104
#define WOFF_M2 1851392

__device__ __forceinline__ void split_plain(const float* W, _Float16* wh, _Float16* wl,
                                            size_t base, int t, int M, int Kk)
{
    int oo = t / Kk, c = t - oo * Kk;
    float v = (oo < M) ? W[(size_t)oo * Kk + c] : 0.f;
    _Float16 h, l;
    split2(v, h, l);
    size_t d = base + (size_t)oo * Kk + swzk(c, oo);
    wh[d] = h; wl[d] = l;
}

__device__ __forceinline__ void split_edge(const float* W, _Float16* wh, _Float16* wl,
                                           size_t base, int t, int O, int C)
{
    int oo = t / C, c = t - oo * C;
    float v;
    if (oo < O) v = W[(size_t)oo * 2 * C + c];
    else { int o2 = oo - O; v = W[(size_t)o2 * 2 * C + C + c] - W[(size_t)o2 * 2 * C + c]; }
    _Float16 h, l;
    split2(v, h, l);
    size_t d = base + (size_t)oo * C + swzk(c, oo);
    wh[d] = h; wl[d] = l;
}

__global__ void mega_prep_k(const float* __restrict__ x,
                            const float* __restrict__ W0, const float* __restrict__ W1,
                            const float* __restrict__ W2, const float* __restrict__ W3,
                            const float* __restrict__ W4, const float* __restrict__ Wm1,
                            const float* __restrict__ Wm2,
                            float* __restrict__ xt, float* __restrict__ wcat32,
                            _Float16* __restrict__ wh, _Float16* __restrict__ wl)
{
    int t = blockIdx.x * 256 + threadIdx.x;
    if (t < T0) {
        int n = t & (Nsz - 1), b = t >> 11;
#pragma unroll
        for (int c = 0; c < 3; c++)
            xt[((size_t)b * 3 + c) * Nsz + n] = x[((size_t)b * Nsz + n) * 3 + c];
    } else if (t < T1) {
        int u = t - T0;
        int oo = u / 3, c = u % 3;
        float a = W0[(size_t)oo * 6 + c];
        float b2 = W0[(size_t)oo * 6 + 3 + c];
        wcat32[(size_t)oo * 3 + c] = a;
        wcat32[(size_t)(64 + oo) * 3 + c] = b2 - a;
    } else if (t < T2) {
        split_edge(W1, wh, wl, WOFF_E1, t - T1, 128, 64);
    } else if (t < T3) {
        split_edge(W2, wh, wl, WOFF_E2, t - T2, 256, 128);
    } else if (t < T4) {
        split_edge(W3, wh, wl, WOFF_E3, t - T3, 512, 256);
    } else if (t < T5) {
        split_plain(W4, wh, wl, WOFF_W4, t - T4, 1024, 960);
    } else if (t < T6) {
        split_plain(Wm1, wh, wl, WOFF_M1, t - T5, 512, 1024);
    } else if (t < T7) {
        split_plain(Wm2, wh, wl, WOFF_M2, t - T6, 70, 512);
    }
}

// xx[b,n] = sum_c v^2 from planes, dropping lo^2 (matches GEMM's form).
// Swizzle-safe: sums whole 32-windows (permutation-invariant).
__global__ void xx_planes_k(const _Float16* __restrict__ catA, const _Float16* __restrict__ catB,
                            float* __restrict__ xx, int off, int C)
{
    int t = blockIdx.x * 256 + threadIdx.x;
    if (t >= Bsz * Nsz) return;
    int n = t & (Nsz - 1), b = t >> 11;
    size_t base = ((size_t)b * Nsz + n) * 1024 + off;
    float s = 0.f;
    for (int c8 = 0; c8 < C / 8; c8++) {
        half8 h = *(const half8*)&catA[base + c8 * 8];
        half8 l = *(const half8*)&catB[base + c8 * 8];
#pragma unroll
        for (int e = 0; e < 8; e++) {
            float vh = (float)h[e];
            float vl = (float)l[e] * INV_LOSCALE;
            s = fmaf(vh, vh, s);
            s = fmaf(2.f * vh, vl, s);
        }
    }
    xx[t] = s;
}

__device__ __forceinline__ unsigned long long shfl_xor64(unsigned long long x, int off)
{
    unsigned lo = __shfl_xor((unsigned)x, off, 64);
    unsigned hi = __shfl_xor((unsigned)(x >> 32), off, 64);
    return ((unsigned long long)hi << 32) | lo;
}

// top-8 per row (JAX semantics: value desc, ties -> lower index)
__global__ void topk8_k(const float* __restrict__ pair, int* __restrict__ idxo)
{
    int lane = threadIdx.x & 63;
    int row = blockIdx.x * 4 + (threadIdx.x >> 6);
    const float* pr = pair + (size_t)row * Nsz;
    unsigned long long t[8] = {0, 0, 0, 0, 0, 0, 0, 0};
    for (int m = lane; m < Nsz; m += 64) {
        float v = pr[m];
        unsigned u = __float_as_uint(v);
        u = (u & 0x80000000u) ? ~u : (u | 0x80000000u);
        unsigned long long key = ((unsigned long long)u << 32) | (0xFFFFFFFFu - (unsigned)m);
#pragma unroll
        for (int j = 7; j >= 1; --j)
            t[j] = (key > t[j - 1]) ? t[j - 1] : ((key > t[j]) ? key : t[j]);
        t[0] = (key > t[0]) ? key : t[0];
    }
    int* op = idxo + (size_t)row * 8;
#pragma unroll
    for (int r = 0; r < 8; r++) {
        unsigned long long best = t[0];
#pragma unroll
        for (int off = 32; off; off >>= 1) {
            unsigned long long o = shfl_xor64(best, off);
            if (o > best) best = o;
        }
        bool own = (t[0] == best);
#pragma unroll
        for (int j = 0; j < 7; j++) t[j] = own ? t[j + 1] : t[j];
        t[7] = own ? 0ull : t[7];
        if (lane == 0) op[r] = (int)(0xFFFFFFFFu - (unsigned)(best & 0xFFFFFFFFull));
    }
}

// gather + max-pool + stats + transpose + split (swizzled write)
// grid (N/64, O/64, B), block 256. part[(o*8+b)*32 + blkx] = {s1,s2}
__global__ void gather_pool_t_k(const float* __restrict__ R, const int* __restrict__ idx,
                                _Float16* __restrict__ catA, _Float16* __restrict__ catB,
                                float* __restrict__ part, int O, int off)
{
    __shared__ float tile[64][65];
    const int tid = threadIdx.x;
    const int lane = tid & 63, w = tid >> 6;
    const int n0 = blockIdx.x * 64, o0 = blockIdx.y * 64, b = blockIdx.z;
    const int n = n0 + lane;

    int id[8];
    {
        const int* ip = idx + ((size_t)b * Nsz + n) * 8;
#pragma unroll
        for (int k = 0; k < 8; k++) id[k] = ip[k];
    }
    const float* Rb = R + (size_t)b * 2 * O * Nsz;
#pragma unroll
    for (int i = 0; i < 16; i++) {
        int o_l = w + i * 4;
        int o = o0 + o_l;
        const float* P = Rb + (size_t)o * Nsz;
        float q = Rb[(size_t)(O + o) * Nsz + n];
        float hmax = -INFINITY, s1 = 0.f, s2 = 0.f;
#pragma unroll
        for (int k = 0; k < 8; k++) {
            float h = P[id[k]] + q;
            hmax = fmaxf(hmax, h);
            s1 += h;
            s2 += h * h;
        }
        tile[o_l][lane] = hmax;
#pragma unroll
        for (int offs = 32; offs; offs >>= 1) {
            s1 += __shfl_xor(s1, offs, 64);
            s2 += __shfl_xor(s2, offs, 64);
        }
        if (lane == 0) {
            size_t pi = ((size_t)o * Bsz + b) * 32 + blockIdx.x;
            part[pi * 2] = s1;
            part[pi * 2 + 1] = s2;
        }
    }
    __syncthreads();
    int n_l = tid >> 2, quad = tid & 3;
    int nrow = n0 + n_l;
    half8 h0, h1, l0, l1;
#pragma unroll
    for (int e = 0; e < 8; e++) {
        _Float16 hh, ll;
        split2(tile[quad * 16 + e][n_l], hh, ll);
        h0[e] = hh; l0[e] = ll;
        split2(tile[quad * 16 + 8 + e][n_l], hh, ll);
        h1[e] = hh; l1[e] = ll;
    }
    size_t rowb = ((size_t)b * Nsz + nrow) * 1024;
    int c0 = off + o0 + quad * 16;
    *(half8*)&catA[rowb + swzk(c0, nrow)] = h0;
    *(half8*)&catA[rowb + swzk(c0 + 8, nrow)] = h1;
    *(half8*)&catB[rowb + swzk(c0, nrow)] = l0;
    *(half8*)&catB[rowb + swzk(c0 + 8, nrow)] = l1;
}

// reduce 256 partials per channel -> stats[2o]=sum, stats[2o+1]=sumsq
__global__ void stats_reduce_k(const float* __restrict__ part, float* __restrict__ stats)
{
    int o2 = blockIdx.x;
    int t = threadIdx.x;
    float s1 = part[((size_t)o2 * 256 + t) * 2];
    float s2 = part[((size_t)o2 * 256 + t) * 2 + 1];
#pragma unroll
    for (int off = 32; off; off >>= 1) { s1 += __shfl_xor(s1, off, 64); s2 += __shfl_xor(s2, off, 64); }
    __shared__ float sh[8];
    int w = t >> 6;
    if ((t & 63) == 0) { sh[w] = s1; sh[4 + w] = s2; }
    __syncthreads();
    if (t == 0) {
        stats[2 * o2] = sh[0] + sh[1] + sh[2] + sh[3];
        stats[2 * o2 + 1] = sh[4] + sh[5] + sh[6] + sh[7];
    }
}

// per-channel stats over (B,N) for fc tensors (B,O,N) fp32
__global__ void fc_stats_k(const float* __restrict__ buf, float* __restrict__ stats, int O)
{
    int oo = blockIdx.x;
    int t = threadIdx.x;
    float s1 = 0.f, s2 = 0.f;
    for (int i = t; i < Bsz * Nsz; i += 256) {
        int b = i >> 11, n = i & (Nsz - 1);
        float v = buf[((size_t)b * O + oo) * Nsz + n];
        s1 += v; s2 += v * v;
    }
#pragma unroll
    for (int off = 32; off; off >>= 1) { s1 += __shfl_xor(s1, off, 64); s2 += __shfl_xor(s2, off, 64); }
    __shared__ float sh[8];
    int w = t >> 6;
    if ((t & 63) == 0) { sh[w] = s1; sh[4 + w] = s2; }
    __syncthreads();
    if (t == 0) {
        stats[2 * oo] = sh[0] + sh[1] + sh[2] + sh[3];
        stats[2 * oo + 1] = sh[4] + sh[5] + sh[6] + sh[7];
    }
}

// in-place BN+lrelu on catT plane slice cols [off, off+O); swizzle-aware
__global__ void bn_t_k(_Float16* __restrict__ catA, _Float16* __restrict__ catB,
                       const float* __restrict__ stats, int off, int O, float invCnt)
{
    int per_n = O / 8;
    size_t t = (size_t)blockIdx.x * 256 + threadIdx.x;
    if (t >= (size_t)Bsz * Nsz * per_n) return;
    int c8 = (int)(t % per_n);
    size_t rest = t / per_n;
    int n = (int)(rest & (Nsz - 1));
    int b = (int)(rest >> 11);
    size_t base = ((size_t)b * Nsz + n) * 1024 + off + c8 * 8;
    // de-swizzle: stored chunk c8 holds original rel chunk ((c8&3) - (n>>1)) & 3
    int oo_base = ((c8 >> 2) << 5) + ((((c8 & 3) - (n >> 1)) & 3) << 3);
    half8 h = *(const half8*)&catA[base];
    half8 l = *(const half8*)&catB[base];
    half8 ho, lo;
#pragma unroll
    for (int e = 0; e < 8; e++) {
        int oo = oo_base + e;
        float mean = stats[2 * oo] * invCnt;
        float var = stats[2 * oo + 1] * invCnt - mean * mean;
        float v = (float)h[e] + (float)l[e] * INV_LOSCALE;
        float z = (v - mean) / sqrtf(var + EPSV);
        z = z >= 0.f ? z : NSLOPE * z;
        _Float16 hh, ll;
        split2(z, hh, ll);
        ho[e] = hh; lo[e] = ll;
    }
    *(half8*)&catA[base] = ho;
    *(half8*)&catB[base] = lo;
}

// fp32 [b][O][n] + BN + lrelu -> swizzled transposed planes [b][n][o] (row stride ldt)
__global__ void bn_split_t_k(const float* __restrict__ src, const float* __restrict__ stats,
                             _Float16* __restrict__ dA, _Float16* __restrict__ dB,
                             int O, int ldt, float invCnt)
{
    __shared__ float tile[64][65];
    const int tid = threadIdx.x;
    const int n0 = blockIdx.x * 64, o0 = blockIdx.y * 64, b = blockIdx.z;
#pragma unroll
    for (int i = 0; i < 16; i++) {
        int flat = tid + 256 * i;
        int o_l = flat >> 6, n_l = flat & 63;
        int oo = o0 + o_l;
        float mean = stats[2 * oo] * invCnt;
        float var = stats[2 * oo + 1] * invCnt - mean * mean;
        float v = src[((size_t)b * O + oo) * Nsz + n0 + n_l];
        float z = (v - mean) / sqrtf(var + EPSV);
        tile[o_l][n_l] = z >= 0.f ? z : NSLOPE * z;
    }
    __syncthreads();
    int n_l = tid >> 2, quad = tid & 3;
    int nrow = n0 + n_l;
    half8 h0, h1, l0, l1;
#pragma unroll
    for (int e = 0; e < 8; e++) {
        _Float16 hh, ll;
        split2(tile[quad * 16 + e][n_l], hh, ll);
        h0[e] = hh; l0[e] = ll;
        split2(tile[quad * 16 + 8 + e][n_l], hh, ll);
        h1[e] = hh; l1[e] = ll;
    }
    size_t rowb = ((size_t)b * Nsz + nrow) * ldt;
    int c0 = o0 + quad * 16;
    *(half8*)&dA[rowb + swzk(c0, nrow)] = h0;
    *(half8*)&dA[rowb + swzk(c0 + 8, nrow)] = h1;
    *(half8*)&dB[rowb + swzk(c0, nrow)] = l0;
    *(half8*)&dB[rowb + swzk(c0 + 8, nrow)] = l1;
}

// argmax_n(logits + gumbel(u)); exact one-hot to out (70,B,N,1)
__global__ void gumbel_onehot_k(const float* __restrict__ logits, const float* __restrict__ u,
                                float* __restrict__ out)
{
    int lane = threadIdx.x & 63;
    int wv = threadIdx.x >> 6;
    int row = blockIdx.x * 4 + wv;      // row = b*70 + o
    int b = row / 70, oo = row % 70;
    const float* L = logits + (size_t)row * Nsz;
    const float* U = u + (size_t)row * Nsz;
    float bv = -INFINITY; int bi = 0x7fffffff;
    for (int n = lane; n < Nsz; n += 64) {
        float g = -logf(-logf(U[n]));
        float z = L[n] + g;
        if (z > bv) { bv = z; bi = n; }
    }
#pragma unroll
    for (int off = 32; off; off >>= 1) {
        float ov = __shfl_xor(bv, off, 64);
        int oi = __shfl_xor(bi, off, 64);
        if (ov > bv || (ov == bv && oi < bi)) { bv = ov; bi = oi; }
    }
    float* Or = out + ((size_t)oo * Bsz + b) * Nsz;
    for (int n = lane; n < Nsz; n += 64) Or[n] = (n == bi) ? 1.f : 0.f;
}

extern "C" void kernel_launch(void* const* d_in, const int* in_sizes, int n_in,
                              void* d_out, int out_size, void* d_ws, size_t ws_size,
                              hipStream_t stream)
{
    (void)in_sizes; (void)n_in; (void)out_size; (void)ws_size;
    const float* x   = (const float*)d_in[0];
    const int*   sn  = (const int*)d_in[1];
    const float* un  = (const float*)d_in[2];
    const float* W0  = (const float*)d_in[3];
    const float* W1  = (const float*)d_in[4];
    const float* W2  = (const float*)d_in[5];
    const float* W3  = (const float*)d_in[6];
    const float* W4  = (const float*)d_in[7];
    const float* Wm1 = (const float*)d_in[8];
    const float* Wm2 = (const float*)d_in[9];
    float* out = (float*)d_out;

    char* ws = (char*)d_ws;
    size_t o = 0;
    _Float16* catA = (_Float16*)(ws + o); o += (size_t)Bsz * Nsz * 1024 * 2;  // 33.5 MB
    _Float16* catB = (_Float16*)(ws + o); o += (size_t)Bsz * Nsz * 1024 * 2;  // 33.5 MB
    float* R       = (float*)(ws + o);    o += (size_t)Bsz * 1024 * Nsz * 4;  // 67 MB
    _Float16* wHi  = (_Float16*)(ws + o); o += (size_t)2 * 1024 * 1024 * 2;   // 4 MB
    _Float16* wLo  = (_Float16*)(ws + o); o += (size_t)2 * 1024 * 1024 * 2;   // 4 MB
    float* xt      = (float*)(ws + o);    o += (size_t)Bsz * 3 * Nsz * 4;
    float* xxb     = (float*)(ws + o);    o += (size_t)Bsz * Nsz * 4;
    float* wcat32  = (float*)(ws + o);    o += 4096;
    float* part    = (float*)(ws + o);    o += (size_t)512 * Bsz * 32 * 2 * 4;
    float* stats   = (float*)(ws + o);    o += 2048 * 4;
    int* idxb      = (int*)(ws + o);      o += (size_t)Bsz * Nsz * Ksz * 4;
    float* logits  = R + (size_t)12 * 1024 * 1024;  // inside R (hm region dead by then)

    const long long catStride = (long long)Nsz * 1024;  // per-batch elems in catT

    // ---- one-shot prep: transpose + all weight processing ----
    mega_prep_k<<<(T7 + 255) / 256, 256, 0, stream>>>(x, W0, W1, W2, W3, W4, Wm1, Wm2,
                                                      xt, wcat32, wHi, wLo);

    // ---- edge layer 1 (C=3, O=64, idx = start_neighs), fp32 path ----
    sgemm_k<<<dim3(32, 2, Bsz), 256, 0, stream>>>(wcat32, 3, xt, 3LL * Nsz, Nsz,
                                                  R, 2LL * 64 * Nsz, Nsz, 128, 3);
    gather_pool_t_k<<<dim3(32, 1, Bsz), 256, 0, stream>>>(R, sn, catA, catB, part, 64, 0);
    stats_reduce_k<<<64, 256, 0, stream>>>(part, stats);
    bn_t_k<<<(int)(((size_t)Bsz * Nsz * 8 + 255) / 256), 256, 0, stream>>>(
        catA, catB, stats, 0, 64, 1.f / 131072.f);

    // ---- edge layers 2..4 ----
    struct LayerDesc { int C; int O; int prevOff; int catOff; size_t woff; };
    LayerDesc L[3] = {
        { 64, 128, 0, 64, WOFF_E1 },
        { 128, 256, 64, 192, WOFF_E2 },
        { 256, 512, 192, 448, WOFF_E3 },
    };
    for (int li = 0; li < 3; li++) {
        int C = L[li].C, O = L[li].O;
        int poff = L[li].prevOff;
        xx_planes_k<<<(Bsz * Nsz + 255) / 256, 256, 0, stream>>>(catA, catB, xxb, poff, C);
        for (int ch = 0; ch < 2; ch++) {
            const _Float16* pA = catA + poff + (size_t)ch * 4 * catStride;
            const _Float16* pB = catB + poff + (size_t)ch * 4 * catStride;
            hgemm_k<1><<<dim3(16, 16, 4), 256, 0, stream>>>(
                pA, pB, catStride, 1024, pA, pB, catStride, 1024,
                R, (long long)Nsz * Nsz, Nsz, Nsz, C, xxb + (size_t)ch * 4 * Nsz);
            topk8_k<<<4 * Nsz / 4, 256, 0, stream>>>(R, idxb + (size_t)ch * 4 * Nsz * Ksz);
        }
        hgemm_k<0><<<dim3(16, 2 * O / 128, Bsz), 256, 0, stream>>>(
            wHi + L[li].woff, wLo + L[li].woff, 0, C, catA + poff, catB + poff, catStride, 1024,
            R, 2LL * O * Nsz, Nsz, 2 * O, C, nullptr);
        gather_pool_t_k<<<dim3(32, O / 64, Bsz), 256, 0, stream>>>(
            R, idxb, catA, catB, part, O, L[li].catOff);
        stats_reduce_k<<<O, 256, 0, stream>>>(part, stats);
        bn_t_k<<<(int)(((size_t)Bsz * Nsz * (O / 8) + 255) / 256), 256, 0, stream>>>(
            catA, catB, stats, L[li].catOff, O, 1.f / 131072.f);
    }

    // ---- fc head ----
    hgemm_k<0><<<dim3(16, 8, Bsz), 256, 0, stream>>>(
        wHi + WOFF_W4, wLo + WOFF_W4, 0, 960, catA, catB, catStride, 1024,
        R, 1024LL * Nsz, Nsz, 1024, 960, nullptr);
    fc_stats_k<<<1024, 256, 0, stream>>>(R, stats, 1024);
    bn_split_t_k<<<dim3(32, 16, Bsz), 256, 0, stream>>>(R, stats, catA, catB, 1024, 1024,
                                                        1.f / 16384.f);
    hgemm_k<0><<<dim3(16, 4, Bsz), 256, 0, stream>>>(
        wHi + WOFF_M1, wLo + WOFF_M1, 0, 1024, catA, catB, catStride, 1024,
        R, 512LL * Nsz, Nsz, 512, 1024, nullptr);
    fc_stats_k<<<512, 256, 0, stream>>>(R, stats, 512);
    bn_split_t_k<<<dim3(32, 8, Bsz), 256, 0, stream>>>(R, stats, catA, catB, 512, 512,
                                                       1.f / 16384.f);
    hgemm_k<0><<<dim3(16, 1, Bsz), 256, 0, stream>>>(
        wHi + WOFF_M2, wLo + WOFF_M2, 0, 512, catA, catB, (long long)Nsz * 512, 512,
        logits, 70LL * Nsz, Nsz, 70, 512, nullptr);

    gumbel_onehot_k<<<(Bsz * 70) / 4, 256, 0, stream>>>(logits, un, out);
}